// Round 14
// baseline (119.587 us; speedup 1.0000x reference)
//
#include <hip/hip_runtime.h>
#include <hip/hip_bf16.h>

#define EPS 1e-6f

typedef float f32x4 __attribute__((ext_vector_type(4)));
typedef __bf16 bf16x8 __attribute__((ext_vector_type(8)));
typedef short short8 __attribute__((ext_vector_type(8)));

static __device__ __forceinline__ short bf16bits(float x) {
    __hip_bfloat16 h = __float2bfloat16(x);
    short s;
    __builtin_memcpy(&s, &h, 2);
    return s;
}
static __device__ __forceinline__ void bsplit(float x, short& h, short& l) {
    __hip_bfloat16 hb = __float2bfloat16(x);
    __builtin_memcpy(&h, &hb, 2);
    float hf = __bfloat162float(hb);
    __hip_bfloat16 lb = __float2bfloat16(x - hf);
    __builtin_memcpy(&l, &lb, 2);
}

// Inline-asm loads for kC (forced counted-vmcnt pipeline, proven R11).
static __device__ __forceinline__ bf16x8 gload16(const short* p) {
    bf16x8 r;
    asm volatile("global_load_dwordx4 %0, %1, off"
                 : "=&v"(r) : "v"(p) : "memory");
    return r;
}
#define WAITV(N)                                                   \
    do {                                                           \
        asm volatile("s_waitcnt vmcnt(" #N ")" ::: "memory");      \
        __builtin_amdgcn_sched_barrier(0);                         \
    } while (0)

// ---- Kernel A: softmax + P23 (f32) + P01T (f32) + P23s_hi (bf16, swizzled) -
__global__ __launch_bounds__(256) void kA(const float* __restrict__ logits,
                                          const float* __restrict__ y_true,
                                          float* __restrict__ P23,
                                          float* __restrict__ P01T,
                                          short* __restrict__ P23s_hi,
                                          int* __restrict__ label) {
    __shared__ float row[64];
    int b = blockIdx.x, t = threadIdx.x;
    if (t < 64) {
        float x = logits[b * 64 + t];
        float m = x;
        for (int mk = 8; mk >= 1; mk >>= 1) m = fmaxf(m, __shfl_xor(m, mk, 16));
        float e = __expf(x - m);
        float s = e;
        for (int mk = 8; mk >= 1; mk >>= 1) s += __shfl_xor(s, mk, 16);
        row[t] = e / s;
    }
    if (t >= 128 && t < 228) {
        int y = t - 128;
        if (y_true[b * 100 + y] > 0.5f) label[b] = y;
    }
    __syncthreads();
    int hi = t >> 4, lo = t & 15;
    float v01 = row[hi] * row[16 + lo];
    float v23 = row[32 + hi] * row[48 + lo];
    P01T[t * 1024 + b] = v01;
    P23[b * 256 + t] = v23;
    int ts = t ^ ((b & 7) << 3);   // XOR swizzle (matches kC LDS read)
    P23s_hi[b * 256 + ts] = bf16bits(v23);
}

// ---- Kernel S: counting sort via bitmask ranks (parallel, deterministic) ---
__global__ __launch_bounds__(1024) void kS(const int* __restrict__ label,
                                           int* __restrict__ bidx,
                                           int* __restrict__ off_g) {
    __shared__ int lab[1024];
    __shared__ unsigned bm[101 * 32];
    __shared__ int hist[101];
    __shared__ int offs[101];
    int t = threadIdx.x;
    lab[t] = label[t];
    if (t < 101) hist[t] = 0;
    for (int i = t; i < 101 * 32; i += 1024) bm[i] = 0u;
    __syncthreads();
    int my = lab[t];
    atomicAdd(&hist[my], 1);
    atomicOr(&bm[my * 32 + (t >> 5)], 1u << (t & 31));
    __syncthreads();
    if (t == 0) {
        int s = 0;
        for (int y = 0; y < 101; ++y) { offs[y] = s; s += hist[y]; }
    }
    __syncthreads();
    int w = t >> 5;
    int rank = 0;
    for (int i = 0; i < w; ++i) rank += __popc(bm[my * 32 + i]);
    rank += __popc(bm[my * 32 + w] & ((1u << (t & 31)) - 1u));
    bidx[offs[my] + rank] = t;
    if (t <= 100) off_g[t] = offs[t];
}

// ---- Kernel P: pre-permute into sorted row order ---------------------------
__global__ __launch_bounds__(256) void kP(const float* __restrict__ P23,
                                          const float* __restrict__ P01T,
                                          const int* __restrict__ bidx,
                                          float* __restrict__ P23sort,
                                          float* __restrict__ P01Ts) {
    int bid = blockIdx.x, t = threadIdx.x;
    if (bid < 1024) {
        P23sort[bid * 256 + t] = P23[bidx[bid] * 256 + t];
    } else {
        int u = bid - 1024;
        for (int i = t; i < 1024; i += 256)
            P01Ts[u * 1024 + i] = P01T[u * 1024 + bidx[i]];   // 4KB-row gather, L1
    }
}

// ---- Kernel NJ: numjoint[u*256+t] = sum_b P01[b,u]P23[b,t]  (hi/lo MFMA) ---
// 16 blocks x (64u x 64t), K=1024 in 32 chunks. 4 waves: wave w -> 16u rows.
__global__ __launch_bounds__(256, 4) void kNJ(const float* __restrict__ P01Ts,
                                              const float* __restrict__ P23sort,
                                              float* __restrict__ numjoint) {
    __shared__ short Bh[4 * 64 * 8];
    __shared__ short Bl[4 * 64 * 8];
    int t = threadIdx.x;
    int ub = (blockIdx.x >> 2) << 6;
    int tb = (blockIdx.x & 3) << 6;
    int lane = t & 63, w = t >> 6;
    int l15 = lane & 15, l4 = lane >> 4;

    const float* pa = P01Ts + (size_t)(ub + w * 16 + l15) * 1024 + (l4 << 3);
    int sr = t >> 3, sc = (t & 7) << 3;

    const f32x4 zero4 = {0.f, 0.f, 0.f, 0.f};
    f32x4 acc0 = zero4, acc1 = zero4, acc2 = zero4, acc3 = zero4;

    #pragma unroll 1
    for (int kc = 0; kc < 32; ++kc) {
        __syncthreads();
        {
            const float* pb = P23sort + (size_t)(kc * 32 + sr) * 256 + tb + sc;
            #pragma unroll
            for (int q = 0; q < 8; ++q) {
                short h, l;
                bsplit(pb[q], h, l);
                int tcl = sc + q;
                int ad = (((tcl >> 4) << 6) + (tcl & 15) + ((sr >> 3) << 4)) * 8 + (sr & 7);
                Bh[ad] = h; Bl[ad] = l;
            }
        }
        __syncthreads();
        union { short8 s; bf16x8 b; } Ah, Al;
        #pragma unroll
        for (int q = 0; q < 8; ++q) {
            short h, l;
            bsplit(pa[kc * 32 + q], h, l);
            Ah.s[q] = h; Al.s[q] = l;
        }
        {
            bf16x8 bh0 = *(const bf16x8*)(Bh + (lane) * 8);
            bf16x8 bl0 = *(const bf16x8*)(Bl + (lane) * 8);
            bf16x8 bh1 = *(const bf16x8*)(Bh + (64 + lane) * 8);
            bf16x8 bl1 = *(const bf16x8*)(Bl + (64 + lane) * 8);
            bf16x8 bh2 = *(const bf16x8*)(Bh + (128 + lane) * 8);
            bf16x8 bl2 = *(const bf16x8*)(Bl + (128 + lane) * 8);
            bf16x8 bh3 = *(const bf16x8*)(Bh + (192 + lane) * 8);
            bf16x8 bl3 = *(const bf16x8*)(Bl + (192 + lane) * 8);
            acc0 = __builtin_amdgcn_mfma_f32_16x16x32_bf16(Ah.b, bh0, acc0, 0, 0, 0);
            acc0 = __builtin_amdgcn_mfma_f32_16x16x32_bf16(Ah.b, bl0, acc0, 0, 0, 0);
            acc0 = __builtin_amdgcn_mfma_f32_16x16x32_bf16(Al.b, bh0, acc0, 0, 0, 0);
            acc1 = __builtin_amdgcn_mfma_f32_16x16x32_bf16(Ah.b, bh1, acc1, 0, 0, 0);
            acc1 = __builtin_amdgcn_mfma_f32_16x16x32_bf16(Ah.b, bl1, acc1, 0, 0, 0);
            acc1 = __builtin_amdgcn_mfma_f32_16x16x32_bf16(Al.b, bh1, acc1, 0, 0, 0);
            acc2 = __builtin_amdgcn_mfma_f32_16x16x32_bf16(Ah.b, bh2, acc2, 0, 0, 0);
            acc2 = __builtin_amdgcn_mfma_f32_16x16x32_bf16(Ah.b, bl2, acc2, 0, 0, 0);
            acc2 = __builtin_amdgcn_mfma_f32_16x16x32_bf16(Al.b, bh2, acc2, 0, 0, 0);
            acc3 = __builtin_amdgcn_mfma_f32_16x16x32_bf16(Ah.b, bh3, acc3, 0, 0, 0);
            acc3 = __builtin_amdgcn_mfma_f32_16x16x32_bf16(Ah.b, bl3, acc3, 0, 0, 0);
            acc3 = __builtin_amdgcn_mfma_f32_16x16x32_bf16(Al.b, bh3, acc3, 0, 0, 0);
        }
    }
    #pragma unroll
    for (int n = 0; n < 4; ++n) {
        f32x4 a = (n == 0) ? acc0 : (n == 1) ? acc1 : (n == 2) ? acc2 : acc3;
        #pragma unroll
        for (int r = 0; r < 4; ++r) {
            int u = ub + w * 16 + (l4 << 2) + r;
            int tc = tb + (n << 4) + l15;
            numjoint[u * 256 + tc] = a[r];
        }
    }
}

// ---- Kernel Y: per-class GEMM -> py -> pyF fragments -----------------------
// grid 256 = (y 0..127) x (t-half). Block: 256u x 128t for one y, K=n_y
// (hi/lo 3-term MFMA). y>=100: zero-fill (padding classes).
__global__ __launch_bounds__(256, 2) void kY(const float* __restrict__ P01Ts,
                                             const float* __restrict__ P23sort,
                                             const int* __restrict__ off_g,
                                             const float* __restrict__ numjoint,
                                             short* __restrict__ pyF) {
    __shared__ short Bh[8 * 64 * 8];
    __shared__ short Bl[8 * 64 * 8];
    __shared__ short ct[4][16 * 128];
    int y = blockIdx.x >> 1;
    int th = blockIdx.x & 1;
    int t = threadIdx.x;
    int lane = t & 63, w = t >> 6;
    int l15 = lane & 15, l4 = lane >> 4;
    int yt = y >> 4, yl = y & 15;

    if (y >= 100) {
        short8 z = {0, 0, 0, 0, 0, 0, 0, 0};
        #pragma unroll
        for (int ut = 0; ut < 4; ++ut)
            #pragma unroll
            for (int rep = 0; rep < 4; ++rep) {
                int c = (rep << 6) + lane;
                int ul = c >> 4, t8 = (c & 15) << 3;
                int u = (w << 6) + (ut << 4) + ul;
                int j0 = u * 256 + (th << 7) + t8;
                size_t sa = ((size_t)((j0 >> 5) * 8 + yt) * 64 + yl + (((j0 >> 3) & 3) << 4)) * 8;
                *(short8*)(pyF + sa) = z;
            }
        return;
    }

    int off = off_g[y];
    int n = off_g[y + 1] - off;
    int nk = (n + 31) >> 5;

    const f32x4 zero4 = {0.f, 0.f, 0.f, 0.f};
    f32x4 acc[4][8];
    #pragma unroll
    for (int a = 0; a < 4; ++a)
        #pragma unroll
        for (int b = 0; b < 8; ++b) acc[a][b] = zero4;

    int sr = t >> 3, sc = (t & 7) << 3;
    const float* paw = P01Ts + (size_t)((w << 6) + l15) * 1024 + off + (l4 << 3);

    #pragma unroll 1
    for (int kc = 0; kc < nk; ++kc) {
        __syncthreads();
        #pragma unroll
        for (int rep = 0; rep < 2; ++rep) {
            int tl0 = (rep << 6) + sc;
            int row = kc * 32 + sr;
            float vals[8];
            if (row < n) {
                const float* pb = P23sort + (size_t)(off + row) * 256 + (th << 7) + tl0;
                #pragma unroll
                for (int q = 0; q < 8; ++q) vals[q] = pb[q];
            } else {
                #pragma unroll
                for (int q = 0; q < 8; ++q) vals[q] = 0.f;
            }
            #pragma unroll
            for (int q = 0; q < 8; ++q) {
                short h, l;
                bsplit(vals[q], h, l);
                int tl = tl0 + q;
                int ad = (((tl >> 4) << 6) + (tl & 15) + ((sr >> 3) << 4)) * 8 + (sr & 7);
                Bh[ad] = h; Bl[ad] = l;
            }
        }
        __syncthreads();
        #pragma unroll
        for (int ut = 0; ut < 4; ++ut) {
            union { short8 s; bf16x8 b; } Ah, Al;
            #pragma unroll
            for (int q = 0; q < 8; ++q) {
                short h, l;
                bsplit(paw[(size_t)ut * 16384 + kc * 32 + q], h, l);
                Ah.s[q] = h; Al.s[q] = l;
            }
            #pragma unroll
            for (int tt = 0; tt < 8; ++tt) {
                bf16x8 bh = *(const bf16x8*)(Bh + ((tt << 6) + lane) * 8);
                bf16x8 bl = *(const bf16x8*)(Bl + ((tt << 6) + lane) * 8);
                acc[ut][tt] = __builtin_amdgcn_mfma_f32_16x16x32_bf16(Ah.b, bh, acc[ut][tt], 0, 0, 0);
                acc[ut][tt] = __builtin_amdgcn_mfma_f32_16x16x32_bf16(Ah.b, bl, acc[ut][tt], 0, 0, 0);
                acc[ut][tt] = __builtin_amdgcn_mfma_f32_16x16x32_bf16(Al.b, bh, acc[ut][tt], 0, 0, 0);
            }
        }
    }

    // epilogue: divide by numjoint, clip, per-wave LDS transpose, store pyF
    #pragma unroll
    for (int ut = 0; ut < 4; ++ut) {
        #pragma unroll
        for (int tt = 0; tt < 8; ++tt) {
            #pragma unroll
            for (int r = 0; r < 4; ++r) {
                int u = (w << 6) + (ut << 4) + (l4 << 2) + r;
                int tg = (th << 7) + (tt << 4) + l15;
                float nj = numjoint[u * 256 + tg];
                float q = fminf(fmaxf(acc[ut][tt][r], EPS) / fmaxf(nj, EPS), 1.0f);
                ct[w][((l4 << 2) + r) * 128 + (tt << 4) + l15] = bf16bits(q);
            }
        }
        asm volatile("s_waitcnt lgkmcnt(0)" ::: "memory");
        __builtin_amdgcn_sched_barrier(0);
        #pragma unroll
        for (int rep = 0; rep < 4; ++rep) {
            int c = (rep << 6) + lane;
            int ul = c >> 4, t8 = (c & 15) << 3;
            short8 v = *(const short8*)(ct[w] + ul * 128 + t8);
            int u = (w << 6) + (ut << 4) + ul;
            int j0 = u * 256 + (th << 7) + t8;
            size_t sa = ((size_t)((j0 >> 5) * 8 + yt) * 64 + yl + (((j0 >> 3) & 3) << 4)) * 8;
            *(short8*)(pyF + sa) = v;
        }
        asm volatile("s_waitcnt lgkmcnt(0)" ::: "memory");
        __builtin_amdgcn_sched_barrier(0);
    }
}

// ---- Kernel C: MFMA GEMM (unchanged).  part += P01*(py x P23^T) ------------
__global__ __launch_bounds__(512, 2) void kC(const short* __restrict__ P23s_hi,
                                             const float* __restrict__ P01T,
                                             const short* __restrict__ pyF,
                                             float* __restrict__ part) {
    __shared__ short Ahi[64 * 256];
    __shared__ float p01s[8 * 64];
    int t = threadIdx.x;
    int bb = blockIdx.x >> 5, uspl = blockIdx.x & 31;
    int bbase = bb << 6;
    int u0 = uspl << 3;

    #pragma unroll
    for (int r = 0; r < 4; ++r) {
        int c = r * 512 + t;
        *(short8*)(Ahi + c * 8) = *(const short8*)(P23s_hi + bbase * 256 + c * 8);
    }
    p01s[t] = P01T[(u0 + (t >> 6)) * 1024 + bbase + (t & 63)];
    __syncthreads();

    int lane = t & 63;
    int wave = t >> 6;
    int wb = wave >> 2, wy = wave & 3;
    int l15 = lane & 15, l4 = lane >> 4;
    int hi8 = l4 << 3;

    int rowA0 = wb * 32 + l15;
    int swz = (rowA0 & 7) << 3;
    const short* pA0h = Ahi + rowA0 * 256;
    const short* pA1h = pA0h + 16 * 256;

    const short* pf = pyF + (size_t)(uspl * 64 * 8 + wy * 2) * 512 + lane * 8;
    int y0 = wy * 32 + l15;

    const f32x4 zero4 = {0.f, 0.f, 0.f, 0.f};
    f32x4 P00 = zero4, P01v = zero4, P10 = zero4, P11 = zero4;
    bf16x8 W0, W1, X0, X1, Y0, Y1, Z0, Z1;

#define COMPUTE(CUR0, CUR1, KS)                                                  \
    {                                                                            \
        int aoff = ((KS) * 32 + hi8) ^ swz;                                      \
        bf16x8 a0h = *(const bf16x8*)(pA0h + aoff);                              \
        bf16x8 a1h = *(const bf16x8*)(pA1h + aoff);                              \
        f32x4 c00 = ((KS) == 0) ? zero4 : Q00;                                   \
        f32x4 c01 = ((KS) == 0) ? zero4 : Q01;                                   \
        f32x4 c10 = ((KS) == 0) ? zero4 : Q10;                                   \
        f32x4 c11 = ((KS) == 0) ? zero4 : Q11;                                   \
        c00 = __builtin_amdgcn_mfma_f32_16x16x32_bf16(a0h, CUR0, c00, 0, 0, 0);  \
        c10 = __builtin_amdgcn_mfma_f32_16x16x32_bf16(a1h, CUR0, c10, 0, 0, 0);  \
        c01 = __builtin_amdgcn_mfma_f32_16x16x32_bf16(a0h, CUR1, c01, 0, 0, 0);  \
        c11 = __builtin_amdgcn_mfma_f32_16x16x32_bf16(a1h, CUR1, c11, 0, 0, 0);  \
        Q00 = c00; Q01 = c01; Q10 = c10; Q11 = c11;                              \
    }
#define STEP(CUR0, CUR1, NXT0, NXT1, KS, S3)    \
    NXT0 = gload16(pf + (S3) * 4096);           \
    NXT1 = gload16(pf + (S3) * 4096 + 512);     \
    WAITV(6);                                   \
    COMPUTE(CUR0, CUR1, KS)

    {
        W0 = gload16(pf);        W1 = gload16(pf + 512);
        X0 = gload16(pf + 4096); X1 = gload16(pf + 4096 + 512);
        Y0 = gload16(pf + 8192); Y1 = gload16(pf + 8192 + 512);
    }

    #pragma unroll 1
    for (int uu = 0; uu < 7; ++uu) {
        int s0 = uu * 8;
        f32x4 Q00, Q01, Q10, Q11;
        STEP(W0, W1, Z0, Z1, 0, s0 + 3)
        STEP(X0, X1, W0, W1, 1, s0 + 4)
        STEP(Y0, Y1, X0, X1, 2, s0 + 5)
        STEP(Z0, Z1, Y0, Y1, 3, s0 + 6)
        STEP(W0, W1, Z0, Z1, 4, s0 + 7)
        STEP(X0, X1, W0, W1, 5, s0 + 8)
        STEP(Y0, Y1, X0, X1, 6, s0 + 9)
        STEP(Z0, Z1, Y0, Y1, 7, s0 + 10)
        f32x4 pv0 = *(const f32x4*)(p01s + uu * 64 + wb * 32 + (l4 << 2));
        f32x4 pv1 = *(const f32x4*)(p01s + uu * 64 + wb * 32 + 16 + (l4 << 2));
        P00 += pv0 * Q00; P01v += pv0 * Q01;
        P10 += pv1 * Q10; P11 += pv1 * Q11;
    }
    {
        f32x4 Q00, Q01, Q10, Q11;
        STEP(W0, W1, Z0, Z1, 0, 59)
        STEP(X0, X1, W0, W1, 1, 60)
        STEP(Y0, Y1, X0, X1, 2, 61)
        STEP(Z0, Z1, Y0, Y1, 3, 62)
        STEP(W0, W1, Z0, Z1, 4, 63)
        WAITV(4); COMPUTE(X0, X1, 5)
        WAITV(2); COMPUTE(Y0, Y1, 6)
        WAITV(0); COMPUTE(Z0, Z1, 7)
        f32x4 pv0 = *(const f32x4*)(p01s + 7 * 64 + wb * 32 + (l4 << 2));
        f32x4 pv1 = *(const f32x4*)(p01s + 7 * 64 + wb * 32 + 16 + (l4 << 2));
        P00 += pv0 * Q00; P01v += pv0 * Q01;
        P10 += pv1 * Q10; P11 += pv1 * Q11;
    }
#undef STEP
#undef COMPUTE

    size_t pbase = (size_t)uspl * 128 * 1024;
    {
        int bg0 = bbase + wb * 32 + (l4 << 2);
        int bg1 = bg0 + 16;
        *(f32x4*)(part + pbase + (size_t)y0 * 1024 + bg0) = P00;
        *(f32x4*)(part + pbase + (size_t)y0 * 1024 + bg1) = P10;
        *(f32x4*)(part + pbase + (size_t)(y0 + 16) * 1024 + bg0) = P01v;
        *(f32x4*)(part + pbase + (size_t)(y0 + 16) * 1024 + bg1) = P11;
    }
}

// ---- Kernel D: reduce 32 u-split partials -> out[b*100+y] ------------------
__global__ __launch_bounds__(256) void kD(const float* __restrict__ part,
                                          float* __restrict__ out) {
    int t = threadIdx.x;
    int y = blockIdx.x >> 2;
    int b = ((blockIdx.x & 3) << 8) + t;
    float s = 0.f;
    for (int q = 0; q < 32; ++q)
        s += part[(((size_t)q * 128 + y) << 10) + b];
    out[(size_t)b * 100 + y] = s;
}

extern "C" void kernel_launch(void* const* d_in, const int* in_sizes, int n_in,
                              void* d_out, int out_size, void* d_ws, size_t ws_size,
                              hipStream_t stream) {
    const float* logits = (const float*)d_in[0];
    const float* y_true = (const float*)d_in[1];
    float* out = (float*)d_out;

    char* ws = (char*)d_ws;
    float* P23      = (float*)(ws + (1u << 20));          // 1 MB
    float* P01T     = (float*)(ws + (2u << 20));          // 1 MB
    short* P23s_hi  = (short*)(ws + (3u << 20));          // 512 KB
    int*   lab      = (int*)(ws + (4u << 20));            // 4 KB
    int*   bidx     = (int*)(ws + (4u << 20) + 4096);
    int*   off_g    = (int*)(ws + (4u << 20) + 8192);     // 101 ints
    float* P23sort  = (float*)(ws + (5u << 20));          // 1 MB
    float* P01Ts    = (float*)(ws + (6u << 20));          // 1 MB (+slack)
    short* pyF      = (short*)(ws + (8u << 20));          // 16 MB fragment layout
    float* numjoint = (float*)(ws + (24u << 20));         // 256 KB
    float* part     = (float*)(ws + (40u << 20));         // 16 MB

    kA<<<1024, 256, 0, stream>>>(logits, y_true, P23, P01T, P23s_hi, lab);
    kS<<<1, 1024, 0, stream>>>(lab, bidx, off_g);
    kP<<<1280, 256, 0, stream>>>(P23, P01T, bidx, P23sort, P01Ts);
    kNJ<<<16, 256, 0, stream>>>(P01Ts, P23sort, numjoint);
    kY<<<256, 256, 0, stream>>>(P01Ts, P23sort, off_g, numjoint, pyF);
    kC<<<512, 512, 0, stream>>>(P23s_hi, P01T, pyF, part);
    kD<<<400, 256, 0, stream>>>(part, out);
}

// Round 15
// 82.183 us; speedup vs baseline: 1.4551x; 1.4551x over previous
//
#include <hip/hip_runtime.h>
#include <hip/hip_bf16.h>

#define EPS 1e-6f

typedef float f32x4 __attribute__((ext_vector_type(4)));
typedef __bf16 bf16x8 __attribute__((ext_vector_type(8)));
typedef short short8 __attribute__((ext_vector_type(8)));

static __device__ __forceinline__ short bf16bits(float x) {
    __hip_bfloat16 h = __float2bfloat16(x);
    short s;
    __builtin_memcpy(&s, &h, 2);
    return s;
}
static __device__ __forceinline__ void bsplit(float x, short& h, short& l) {
    __hip_bfloat16 hb = __float2bfloat16(x);
    __builtin_memcpy(&h, &hb, 2);
    float hf = __bfloat162float(hb);
    __hip_bfloat16 lb = __float2bfloat16(x - hf);
    __builtin_memcpy(&l, &lb, 2);
}

// Inline-asm loads for kC (forced counted-vmcnt pipeline, proven R11).
static __device__ __forceinline__ bf16x8 gload16(const short* p) {
    bf16x8 r;
    asm volatile("global_load_dwordx4 %0, %1, off"
                 : "=&v"(r) : "v"(p) : "memory");
    return r;
}
#define WAITV(N)                                                   \
    do {                                                           \
        asm volatile("s_waitcnt vmcnt(" #N ")" ::: "memory");      \
        __builtin_amdgcn_sched_barrier(0);                         \
    } while (0)

// ---- Kernel A: softmax + P23 (f32) + P01T (f32) + P23s_hi (bf16, swizzled) -
__global__ __launch_bounds__(256) void kA(const float* __restrict__ logits,
                                          const float* __restrict__ y_true,
                                          float* __restrict__ P23,
                                          float* __restrict__ P01T,
                                          short* __restrict__ P23s_hi,
                                          int* __restrict__ label) {
    __shared__ float row[64];
    int b = blockIdx.x, t = threadIdx.x;
    if (t < 64) {
        float x = logits[b * 64 + t];
        float m = x;
        for (int mk = 8; mk >= 1; mk >>= 1) m = fmaxf(m, __shfl_xor(m, mk, 16));
        float e = __expf(x - m);
        float s = e;
        for (int mk = 8; mk >= 1; mk >>= 1) s += __shfl_xor(s, mk, 16);
        row[t] = e / s;
    }
    if (t >= 128 && t < 228) {
        int y = t - 128;
        if (y_true[b * 100 + y] > 0.5f) label[b] = y;
    }
    __syncthreads();
    int hi = t >> 4, lo = t & 15;
    float v01 = row[hi] * row[16 + lo];
    float v23 = row[32 + hi] * row[48 + lo];
    P01T[t * 1024 + b] = v01;
    P23[b * 256 + t] = v23;
    int ts = t ^ ((b & 7) << 3);   // XOR swizzle (matches kC LDS read)
    P23s_hi[b * 256 + ts] = bf16bits(v23);
}

// ---- Kernel S: counting sort via bitmask ranks + zero numjoint -------------
__global__ __launch_bounds__(1024) void kS(const int* __restrict__ label,
                                           int* __restrict__ bidx,
                                           int* __restrict__ off_g,
                                           float* __restrict__ numjoint) {
    __shared__ int lab[1024];
    __shared__ unsigned bm[101 * 32];
    __shared__ int hist[101];
    __shared__ int offs[101];
    int t = threadIdx.x;
    for (int i = t; i < 65536; i += 1024) numjoint[i] = 0.f;
    lab[t] = label[t];
    if (t < 101) hist[t] = 0;
    for (int i = t; i < 101 * 32; i += 1024) bm[i] = 0u;
    __syncthreads();
    int my = lab[t];
    atomicAdd(&hist[my], 1);
    atomicOr(&bm[my * 32 + (t >> 5)], 1u << (t & 31));
    __syncthreads();
    if (t == 0) {
        int s = 0;
        for (int y = 0; y < 101; ++y) { offs[y] = s; s += hist[y]; }
    }
    __syncthreads();
    int w = t >> 5;
    int rank = 0;
    for (int i = 0; i < w; ++i) rank += __popc(bm[my * 32 + i]);
    rank += __popc(bm[my * 32 + w] & ((1u << (t & 31)) - 1u));
    bidx[offs[my] + rank] = t;
    if (t <= 100) off_g[t] = offs[t];
}

// ---- Kernel P: pre-permute into sorted row order ---------------------------
__global__ __launch_bounds__(256) void kP(const float* __restrict__ P23,
                                          const float* __restrict__ P01T,
                                          const int* __restrict__ bidx,
                                          float* __restrict__ P23sort,
                                          float* __restrict__ P01Ts) {
    int bid = blockIdx.x, t = threadIdx.x;
    if (bid < 1024) {
        P23sort[bid * 256 + t] = P23[bidx[bid] * 256 + t];
    } else {
        int u = bid - 1024;
        for (int i = t; i < 1024; i += 256)
            P01Ts[u * 1024 + i] = P01T[u * 1024 + bidx[i]];   // 4KB-row gather, L1
    }
}

// ---- Kernel NJ: numjoint[u*256+t] += sum_{K-slice} P01[b,u]P23[b,t] --------
// grid 256 = 4 ub x 4 tb x 16 K-slices (K=64 each, 2 chunks). Global f32
// atomics commit (16 fixed contributors; ulp-order noise << bf16 rounding).
__global__ __launch_bounds__(256, 4) void kNJ(const float* __restrict__ P01Ts,
                                              const float* __restrict__ P23sort,
                                              float* __restrict__ numjoint) {
    __shared__ short Bh[4 * 64 * 8];
    __shared__ short Bl[4 * 64 * 8];
    int t = threadIdx.x;
    int bid = blockIdx.x;
    int ub = (bid & 3) << 6;
    int tb = ((bid >> 2) & 3) << 6;
    int koff = (bid >> 4) << 6;          // 0..960, step 64
    int lane = t & 63, w = t >> 6;
    int l15 = lane & 15, l4 = lane >> 4;

    const float* pa = P01Ts + (size_t)(ub + w * 16 + l15) * 1024 + koff + (l4 << 3);
    int sr = t >> 3, sc = (t & 7) << 3;

    const f32x4 zero4 = {0.f, 0.f, 0.f, 0.f};
    f32x4 acc0 = zero4, acc1 = zero4, acc2 = zero4, acc3 = zero4;

    #pragma unroll
    for (int kc = 0; kc < 2; ++kc) {
        __syncthreads();
        {
            const float* pb = P23sort + (size_t)(koff + kc * 32 + sr) * 256 + tb + sc;
            #pragma unroll
            for (int q = 0; q < 8; ++q) {
                short h, l;
                bsplit(pb[q], h, l);
                int tcl = sc + q;
                int ad = (((tcl >> 4) << 6) + (tcl & 15) + ((sr >> 3) << 4)) * 8 + (sr & 7);
                Bh[ad] = h; Bl[ad] = l;
            }
        }
        __syncthreads();
        union { short8 s; bf16x8 b; } Ah, Al;
        #pragma unroll
        for (int q = 0; q < 8; ++q) {
            short h, l;
            bsplit(pa[kc * 32 + q], h, l);
            Ah.s[q] = h; Al.s[q] = l;
        }
        {
            bf16x8 bh0 = *(const bf16x8*)(Bh + (lane) * 8);
            bf16x8 bl0 = *(const bf16x8*)(Bl + (lane) * 8);
            bf16x8 bh1 = *(const bf16x8*)(Bh + (64 + lane) * 8);
            bf16x8 bl1 = *(const bf16x8*)(Bl + (64 + lane) * 8);
            bf16x8 bh2 = *(const bf16x8*)(Bh + (128 + lane) * 8);
            bf16x8 bl2 = *(const bf16x8*)(Bl + (128 + lane) * 8);
            bf16x8 bh3 = *(const bf16x8*)(Bh + (192 + lane) * 8);
            bf16x8 bl3 = *(const bf16x8*)(Bl + (192 + lane) * 8);
            acc0 = __builtin_amdgcn_mfma_f32_16x16x32_bf16(Ah.b, bh0, acc0, 0, 0, 0);
            acc0 = __builtin_amdgcn_mfma_f32_16x16x32_bf16(Ah.b, bl0, acc0, 0, 0, 0);
            acc0 = __builtin_amdgcn_mfma_f32_16x16x32_bf16(Al.b, bh0, acc0, 0, 0, 0);
            acc1 = __builtin_amdgcn_mfma_f32_16x16x32_bf16(Ah.b, bh1, acc1, 0, 0, 0);
            acc1 = __builtin_amdgcn_mfma_f32_16x16x32_bf16(Ah.b, bl1, acc1, 0, 0, 0);
            acc1 = __builtin_amdgcn_mfma_f32_16x16x32_bf16(Al.b, bh1, acc1, 0, 0, 0);
            acc2 = __builtin_amdgcn_mfma_f32_16x16x32_bf16(Ah.b, bh2, acc2, 0, 0, 0);
            acc2 = __builtin_amdgcn_mfma_f32_16x16x32_bf16(Ah.b, bl2, acc2, 0, 0, 0);
            acc2 = __builtin_amdgcn_mfma_f32_16x16x32_bf16(Al.b, bh2, acc2, 0, 0, 0);
            acc3 = __builtin_amdgcn_mfma_f32_16x16x32_bf16(Ah.b, bh3, acc3, 0, 0, 0);
            acc3 = __builtin_amdgcn_mfma_f32_16x16x32_bf16(Ah.b, bl3, acc3, 0, 0, 0);
            acc3 = __builtin_amdgcn_mfma_f32_16x16x32_bf16(Al.b, bh3, acc3, 0, 0, 0);
        }
    }
    #pragma unroll
    for (int n = 0; n < 4; ++n) {
        f32x4 a = (n == 0) ? acc0 : (n == 1) ? acc1 : (n == 2) ? acc2 : acc3;
        #pragma unroll
        for (int r = 0; r < 4; ++r) {
            int u = ub + w * 16 + (l4 << 2) + r;
            int tc = tb + (n << 4) + l15;
            atomicAdd(&numjoint[u * 256 + tc], a[r]);
        }
    }
}

// ---- Kernel Y: per-class GEMM -> py -> pyF fragments -----------------------
// grid 256 = (y 0..127) x (t-half). Block: 256u x 128t for one y, K=n_y
// (hi/lo 3-term MFMA). y>=100: zero-fill (padding classes).
__global__ __launch_bounds__(256, 2) void kY(const float* __restrict__ P01Ts,
                                             const float* __restrict__ P23sort,
                                             const int* __restrict__ off_g,
                                             const float* __restrict__ numjoint,
                                             short* __restrict__ pyF) {
    __shared__ short Bh[8 * 64 * 8];
    __shared__ short Bl[8 * 64 * 8];
    __shared__ short ct[4][16 * 128];
    int y = blockIdx.x >> 1;
    int th = blockIdx.x & 1;
    int t = threadIdx.x;
    int lane = t & 63, w = t >> 6;
    int l15 = lane & 15, l4 = lane >> 4;
    int yt = y >> 4, yl = y & 15;

    if (y >= 100) {
        short8 z = {0, 0, 0, 0, 0, 0, 0, 0};
        #pragma unroll
        for (int ut = 0; ut < 4; ++ut)
            #pragma unroll
            for (int rep = 0; rep < 4; ++rep) {
                int c = (rep << 6) + lane;
                int ul = c >> 4, t8 = (c & 15) << 3;
                int u = (w << 6) + (ut << 4) + ul;
                int j0 = u * 256 + (th << 7) + t8;
                size_t sa = ((size_t)((j0 >> 5) * 8 + yt) * 64 + yl + (((j0 >> 3) & 3) << 4)) * 8;
                *(short8*)(pyF + sa) = z;
            }
        return;
    }

    int off = off_g[y];
    int n = off_g[y + 1] - off;
    int nk = (n + 31) >> 5;

    const f32x4 zero4 = {0.f, 0.f, 0.f, 0.f};
    f32x4 acc[4][8];
    #pragma unroll
    for (int a = 0; a < 4; ++a)
        #pragma unroll
        for (int b = 0; b < 8; ++b) acc[a][b] = zero4;

    int sr = t >> 3, sc = (t & 7) << 3;
    const float* paw = P01Ts + (size_t)((w << 6) + l15) * 1024 + off + (l4 << 3);

    #pragma unroll 1
    for (int kc = 0; kc < nk; ++kc) {
        __syncthreads();
        #pragma unroll
        for (int rep = 0; rep < 2; ++rep) {
            int tl0 = (rep << 6) + sc;
            int row = kc * 32 + sr;
            float vals[8];
            if (row < n) {
                const float* pb = P23sort + (size_t)(off + row) * 256 + (th << 7) + tl0;
                #pragma unroll
                for (int q = 0; q < 8; ++q) vals[q] = pb[q];
            } else {
                #pragma unroll
                for (int q = 0; q < 8; ++q) vals[q] = 0.f;
            }
            #pragma unroll
            for (int q = 0; q < 8; ++q) {
                short h, l;
                bsplit(vals[q], h, l);
                int tl = tl0 + q;
                int ad = (((tl >> 4) << 6) + (tl & 15) + ((sr >> 3) << 4)) * 8 + (sr & 7);
                Bh[ad] = h; Bl[ad] = l;
            }
        }
        __syncthreads();
        #pragma unroll
        for (int ut = 0; ut < 4; ++ut) {
            union { short8 s; bf16x8 b; } Ah, Al;
            #pragma unroll
            for (int q = 0; q < 8; ++q) {
                short h, l;
                bsplit(paw[(size_t)ut * 16384 + kc * 32 + q], h, l);
                Ah.s[q] = h; Al.s[q] = l;
            }
            #pragma unroll
            for (int tt = 0; tt < 8; ++tt) {
                bf16x8 bh = *(const bf16x8*)(Bh + ((tt << 6) + lane) * 8);
                bf16x8 bl = *(const bf16x8*)(Bl + ((tt << 6) + lane) * 8);
                acc[ut][tt] = __builtin_amdgcn_mfma_f32_16x16x32_bf16(Ah.b, bh, acc[ut][tt], 0, 0, 0);
                acc[ut][tt] = __builtin_amdgcn_mfma_f32_16x16x32_bf16(Ah.b, bl, acc[ut][tt], 0, 0, 0);
                acc[ut][tt] = __builtin_amdgcn_mfma_f32_16x16x32_bf16(Al.b, bh, acc[ut][tt], 0, 0, 0);
            }
        }
    }

    // epilogue: divide by numjoint, clip, per-wave LDS transpose, store pyF
    #pragma unroll
    for (int ut = 0; ut < 4; ++ut) {
        #pragma unroll
        for (int tt = 0; tt < 8; ++tt) {
            #pragma unroll
            for (int r = 0; r < 4; ++r) {
                int u = (w << 6) + (ut << 4) + (l4 << 2) + r;
                int tg = (th << 7) + (tt << 4) + l15;
                float nj = numjoint[u * 256 + tg];
                float q = fminf(fmaxf(acc[ut][tt][r], EPS) / fmaxf(nj, EPS), 1.0f);
                ct[w][((l4 << 2) + r) * 128 + (tt << 4) + l15] = bf16bits(q);
            }
        }
        asm volatile("s_waitcnt lgkmcnt(0)" ::: "memory");
        __builtin_amdgcn_sched_barrier(0);
        #pragma unroll
        for (int rep = 0; rep < 4; ++rep) {
            int c = (rep << 6) + lane;
            int ul = c >> 4, t8 = (c & 15) << 3;
            short8 v = *(const short8*)(ct[w] + ul * 128 + t8);
            int u = (w << 6) + (ut << 4) + ul;
            int j0 = u * 256 + (th << 7) + t8;
            size_t sa = ((size_t)((j0 >> 5) * 8 + yt) * 64 + yl + (((j0 >> 3) & 3) << 4)) * 8;
            *(short8*)(pyF + sa) = v;
        }
        asm volatile("s_waitcnt lgkmcnt(0)" ::: "memory");
        __builtin_amdgcn_sched_barrier(0);
    }
}

// ---- Kernel C: MFMA GEMM (unchanged).  part += P01*(py x P23^T) ------------
__global__ __launch_bounds__(512, 2) void kC(const short* __restrict__ P23s_hi,
                                             const float* __restrict__ P01T,
                                             const short* __restrict__ pyF,
                                             float* __restrict__ part) {
    __shared__ short Ahi[64 * 256];
    __shared__ float p01s[8 * 64];
    int t = threadIdx.x;
    int bb = blockIdx.x >> 5, uspl = blockIdx.x & 31;
    int bbase = bb << 6;
    int u0 = uspl << 3;

    #pragma unroll
    for (int r = 0; r < 4; ++r) {
        int c = r * 512 + t;
        *(short8*)(Ahi + c * 8) = *(const short8*)(P23s_hi + bbase * 256 + c * 8);
    }
    p01s[t] = P01T[(u0 + (t >> 6)) * 1024 + bbase + (t & 63)];
    __syncthreads();

    int lane = t & 63;
    int wave = t >> 6;
    int wb = wave >> 2, wy = wave & 3;
    int l15 = lane & 15, l4 = lane >> 4;
    int hi8 = l4 << 3;

    int rowA0 = wb * 32 + l15;
    int swz = (rowA0 & 7) << 3;
    const short* pA0h = Ahi + rowA0 * 256;
    const short* pA1h = pA0h + 16 * 256;

    const short* pf = pyF + (size_t)(uspl * 64 * 8 + wy * 2) * 512 + lane * 8;
    int y0 = wy * 32 + l15;

    const f32x4 zero4 = {0.f, 0.f, 0.f, 0.f};
    f32x4 P00 = zero4, P01v = zero4, P10 = zero4, P11 = zero4;
    bf16x8 W0, W1, X0, X1, Y0, Y1, Z0, Z1;

#define COMPUTE(CUR0, CUR1, KS)                                                  \
    {                                                                            \
        int aoff = ((KS) * 32 + hi8) ^ swz;                                      \
        bf16x8 a0h = *(const bf16x8*)(pA0h + aoff);                              \
        bf16x8 a1h = *(const bf16x8*)(pA1h + aoff);                              \
        f32x4 c00 = ((KS) == 0) ? zero4 : Q00;                                   \
        f32x4 c01 = ((KS) == 0) ? zero4 : Q01;                                   \
        f32x4 c10 = ((KS) == 0) ? zero4 : Q10;                                   \
        f32x4 c11 = ((KS) == 0) ? zero4 : Q11;                                   \
        c00 = __builtin_amdgcn_mfma_f32_16x16x32_bf16(a0h, CUR0, c00, 0, 0, 0);  \
        c10 = __builtin_amdgcn_mfma_f32_16x16x32_bf16(a1h, CUR0, c10, 0, 0, 0);  \
        c01 = __builtin_amdgcn_mfma_f32_16x16x32_bf16(a0h, CUR1, c01, 0, 0, 0);  \
        c11 = __builtin_amdgcn_mfma_f32_16x16x32_bf16(a1h, CUR1, c11, 0, 0, 0);  \
        Q00 = c00; Q01 = c01; Q10 = c10; Q11 = c11;                              \
    }
#define STEP(CUR0, CUR1, NXT0, NXT1, KS, S3)    \
    NXT0 = gload16(pf + (S3) * 4096);           \
    NXT1 = gload16(pf + (S3) * 4096 + 512);     \
    WAITV(6);                                   \
    COMPUTE(CUR0, CUR1, KS)

    {
        W0 = gload16(pf);        W1 = gload16(pf + 512);
        X0 = gload16(pf + 4096); X1 = gload16(pf + 4096 + 512);
        Y0 = gload16(pf + 8192); Y1 = gload16(pf + 8192 + 512);
    }

    #pragma unroll 1
    for (int uu = 0; uu < 7; ++uu) {
        int s0 = uu * 8;
        f32x4 Q00, Q01, Q10, Q11;
        STEP(W0, W1, Z0, Z1, 0, s0 + 3)
        STEP(X0, X1, W0, W1, 1, s0 + 4)
        STEP(Y0, Y1, X0, X1, 2, s0 + 5)
        STEP(Z0, Z1, Y0, Y1, 3, s0 + 6)
        STEP(W0, W1, Z0, Z1, 4, s0 + 7)
        STEP(X0, X1, W0, W1, 5, s0 + 8)
        STEP(Y0, Y1, X0, X1, 6, s0 + 9)
        STEP(Z0, Z1, Y0, Y1, 7, s0 + 10)
        f32x4 pv0 = *(const f32x4*)(p01s + uu * 64 + wb * 32 + (l4 << 2));
        f32x4 pv1 = *(const f32x4*)(p01s + uu * 64 + wb * 32 + 16 + (l4 << 2));
        P00 += pv0 * Q00; P01v += pv0 * Q01;
        P10 += pv1 * Q10; P11 += pv1 * Q11;
    }
    {
        f32x4 Q00, Q01, Q10, Q11;
        STEP(W0, W1, Z0, Z1, 0, 59)
        STEP(X0, X1, W0, W1, 1, 60)
        STEP(Y0, Y1, X0, X1, 2, 61)
        STEP(Z0, Z1, Y0, Y1, 3, 62)
        STEP(W0, W1, Z0, Z1, 4, 63)
        WAITV(4); COMPUTE(X0, X1, 5)
        WAITV(2); COMPUTE(Y0, Y1, 6)
        WAITV(0); COMPUTE(Z0, Z1, 7)
        f32x4 pv0 = *(const f32x4*)(p01s + 7 * 64 + wb * 32 + (l4 << 2));
        f32x4 pv1 = *(const f32x4*)(p01s + 7 * 64 + wb * 32 + 16 + (l4 << 2));
        P00 += pv0 * Q00; P01v += pv0 * Q01;
        P10 += pv1 * Q10; P11 += pv1 * Q11;
    }
#undef STEP
#undef COMPUTE

    size_t pbase = (size_t)uspl * 128 * 1024;
    {
        int bg0 = bbase + wb * 32 + (l4 << 2);
        int bg1 = bg0 + 16;
        *(f32x4*)(part + pbase + (size_t)y0 * 1024 + bg0) = P00;
        *(f32x4*)(part + pbase + (size_t)y0 * 1024 + bg1) = P10;
        *(f32x4*)(part + pbase + (size_t)(y0 + 16) * 1024 + bg0) = P01v;
        *(f32x4*)(part + pbase + (size_t)(y0 + 16) * 1024 + bg1) = P11;
    }
}

// ---- Kernel D: reduce 32 u-split partials -> out[b*100+y] ------------------
__global__ __launch_bounds__(256) void kD(const float* __restrict__ part,
                                          float* __restrict__ out) {
    int t = threadIdx.x;
    int y = blockIdx.x >> 2;
    int b = ((blockIdx.x & 3) << 8) + t;
    float s = 0.f;
    for (int q = 0; q < 32; ++q)
        s += part[(((size_t)q * 128 + y) << 10) + b];
    out[(size_t)b * 100 + y] = s;
}

extern "C" void kernel_launch(void* const* d_in, const int* in_sizes, int n_in,
                              void* d_out, int out_size, void* d_ws, size_t ws_size,
                              hipStream_t stream) {
    const float* logits = (const float*)d_in[0];
    const float* y_true = (const float*)d_in[1];
    float* out = (float*)d_out;

    char* ws = (char*)d_ws;
    float* P23      = (float*)(ws + (1u << 20));          // 1 MB
    float* P01T     = (float*)(ws + (2u << 20));          // 1 MB
    short* P23s_hi  = (short*)(ws + (3u << 20));          // 512 KB
    int*   lab      = (int*)(ws + (4u << 20));            // 4 KB
    int*   bidx     = (int*)(ws + (4u << 20) + 4096);
    int*   off_g    = (int*)(ws + (4u << 20) + 8192);     // 101 ints
    float* P23sort  = (float*)(ws + (5u << 20));          // 1 MB
    float* P01Ts    = (float*)(ws + (6u << 20));          // 1 MB (+slack)
    short* pyF      = (short*)(ws + (8u << 20));          // 16 MB fragment layout
    float* numjoint = (float*)(ws + (24u << 20));         // 256 KB
    float* part     = (float*)(ws + (40u << 20));         // 16 MB

    kA<<<1024, 256, 0, stream>>>(logits, y_true, P23, P01T, P23s_hi, lab);
    kS<<<1, 1024, 0, stream>>>(lab, bidx, off_g, numjoint);
    kP<<<1280, 256, 0, stream>>>(P23, P01T, bidx, P23sort, P01Ts);
    kNJ<<<256, 256, 0, stream>>>(P01Ts, P23sort, numjoint);
    kY<<<256, 256, 0, stream>>>(P01Ts, P23sort, off_g, numjoint, pyF);
    kC<<<512, 512, 0, stream>>>(P23s_hi, P01T, pyF, part);
    kD<<<400, 256, 0, stream>>>(part, out);
}

// Round 16
// 75.946 us; speedup vs baseline: 1.5746x; 1.0821x over previous
//
#include <hip/hip_runtime.h>
#include <hip/hip_bf16.h>

#define EPS 1e-6f

typedef float f32x4 __attribute__((ext_vector_type(4)));
typedef __bf16 bf16x8 __attribute__((ext_vector_type(8)));
typedef short short8 __attribute__((ext_vector_type(8)));

static __device__ __forceinline__ short bf16bits(float x) {
    __hip_bfloat16 h = __float2bfloat16(x);
    short s;
    __builtin_memcpy(&s, &h, 2);
    return s;
}
static __device__ __forceinline__ void bsplit(float x, short& h, short& l) {
    __hip_bfloat16 hb = __float2bfloat16(x);
    __builtin_memcpy(&h, &hb, 2);
    float hf = __bfloat162float(hb);
    __hip_bfloat16 lb = __float2bfloat16(x - hf);
    __builtin_memcpy(&l, &lb, 2);
}

// Inline-asm loads for kC (forced counted-vmcnt pipeline, proven R11).
static __device__ __forceinline__ bf16x8 gload16(const short* p) {
    bf16x8 r;
    asm volatile("global_load_dwordx4 %0, %1, off"
                 : "=&v"(r) : "v"(p) : "memory");
    return r;
}
#define WAITV(N)                                                   \
    do {                                                           \
        asm volatile("s_waitcnt vmcnt(" #N ")" ::: "memory");      \
        __builtin_amdgcn_sched_barrier(0);                         \
    } while (0)

// ---- Kernel A: softmax + P23/P01/P01T + P23s_hi (swizzled) + zero numjoint -
__global__ __launch_bounds__(256) void kA(const float* __restrict__ logits,
                                          const float* __restrict__ y_true,
                                          float* __restrict__ P23,
                                          float* __restrict__ P01,
                                          float* __restrict__ P01T,
                                          short* __restrict__ P23s_hi,
                                          int* __restrict__ label,
                                          float* __restrict__ numjoint) {
    __shared__ float row[64];
    int b = blockIdx.x, t = threadIdx.x;
    if (t < 64) {
        float x = logits[b * 64 + t];
        float m = x;
        for (int mk = 8; mk >= 1; mk >>= 1) m = fmaxf(m, __shfl_xor(m, mk, 16));
        float e = __expf(x - m);
        float s = e;
        for (int mk = 8; mk >= 1; mk >>= 1) s += __shfl_xor(s, mk, 16);
        row[t] = e / s;
    }
    if (t >= 128 && t < 228) {
        int y = t - 128;
        if (y_true[b * 100 + y] > 0.5f) label[b] = y;
    }
    if (t < 64) numjoint[b * 64 + t] = 0.f;   // disjoint slices; done before kSNJ
    __syncthreads();
    int hi = t >> 4, lo = t & 15;
    float v01 = row[hi] * row[16 + lo];
    float v23 = row[32 + hi] * row[48 + lo];
    P01[b * 256 + t] = v01;
    P01T[t * 1024 + b] = v01;
    P23[b * 256 + t] = v23;
    int ts = t ^ ((b & 7) << 3);   // XOR swizzle (matches kC LDS read)
    P23s_hi[b * 256 + ts] = bf16bits(v23);
}

// ---- Kernel SNJ: blocks 0..255 = numjoint partial GEMMs (unsorted inputs,
// order-independent); block 256 = counting sort (bitmask ranks, 256 thr). ----
__global__ __launch_bounds__(256, 4) void kSNJ(const float* __restrict__ P01T,
                                               const float* __restrict__ P23,
                                               const int* __restrict__ label,
                                               int* __restrict__ bidx,
                                               int* __restrict__ off_g,
                                               float* __restrict__ numjoint) {
    int t = threadIdx.x;
    int bid = blockIdx.x;

    if (bid == 256) {   // ---- sort block ----
        __shared__ int lab[1024];
        __shared__ unsigned bm[101 * 32];
        __shared__ int hist[101];
        __shared__ int offs[101];
        for (int i = t; i < 1024; i += 256) lab[i] = label[i];
        if (t < 101) hist[t] = 0;
        for (int i = t; i < 101 * 32; i += 256) bm[i] = 0u;
        __syncthreads();
        for (int i = t; i < 1024; i += 256) {
            int my = lab[i];
            atomicAdd(&hist[my], 1);
            atomicOr(&bm[my * 32 + (i >> 5)], 1u << (i & 31));
        }
        __syncthreads();
        if (t == 0) {
            int s = 0;
            for (int y = 0; y < 101; ++y) { offs[y] = s; s += hist[y]; }
        }
        __syncthreads();
        for (int i = t; i < 1024; i += 256) {
            int my = lab[i];
            int w = i >> 5;
            int rank = 0;
            for (int q = 0; q < 32; ++q)
                if (q < w) rank += __popc(bm[my * 32 + q]);
            rank += __popc(bm[my * 32 + w] & ((1u << (i & 31)) - 1u));
            bidx[offs[my] + rank] = i;
        }
        if (t <= 100) off_g[t] = offs[t];
        return;
    }

    // ---- NJ slice: numjoint[u,t] += sum_{K-slice} P01[b,u]P23[b,t] ----
    __shared__ short Bh[4 * 64 * 8];
    __shared__ short Bl[4 * 64 * 8];
    int ub = (bid & 3) << 6;
    int tb = ((bid >> 2) & 3) << 6;
    int koff = (bid >> 4) << 6;          // 0..960, step 64
    int lane = t & 63, w = t >> 6;
    int l15 = lane & 15, l4 = lane >> 4;

    const float* pa = P01T + (size_t)(ub + w * 16 + l15) * 1024 + koff + (l4 << 3);
    int sr = t >> 3, sc = (t & 7) << 3;

    const f32x4 zero4 = {0.f, 0.f, 0.f, 0.f};
    f32x4 acc0 = zero4, acc1 = zero4, acc2 = zero4, acc3 = zero4;

    #pragma unroll
    for (int kc = 0; kc < 2; ++kc) {
        __syncthreads();
        {
            const float* pb = P23 + (size_t)(koff + kc * 32 + sr) * 256 + tb + sc;
            #pragma unroll
            for (int q = 0; q < 8; ++q) {
                short h, l;
                bsplit(pb[q], h, l);
                int tcl = sc + q;
                int ad = (((tcl >> 4) << 6) + (tcl & 15) + ((sr >> 3) << 4)) * 8 + (sr & 7);
                Bh[ad] = h; Bl[ad] = l;
            }
        }
        __syncthreads();
        union { short8 s; bf16x8 b; } Ah, Al;
        #pragma unroll
        for (int q = 0; q < 8; ++q) {
            short h, l;
            bsplit(pa[kc * 32 + q], h, l);
            Ah.s[q] = h; Al.s[q] = l;
        }
        {
            bf16x8 bh0 = *(const bf16x8*)(Bh + (lane) * 8);
            bf16x8 bl0 = *(const bf16x8*)(Bl + (lane) * 8);
            bf16x8 bh1 = *(const bf16x8*)(Bh + (64 + lane) * 8);
            bf16x8 bl1 = *(const bf16x8*)(Bl + (64 + lane) * 8);
            bf16x8 bh2 = *(const bf16x8*)(Bh + (128 + lane) * 8);
            bf16x8 bl2 = *(const bf16x8*)(Bl + (128 + lane) * 8);
            bf16x8 bh3 = *(const bf16x8*)(Bh + (192 + lane) * 8);
            bf16x8 bl3 = *(const bf16x8*)(Bl + (192 + lane) * 8);
            acc0 = __builtin_amdgcn_mfma_f32_16x16x32_bf16(Ah.b, bh0, acc0, 0, 0, 0);
            acc0 = __builtin_amdgcn_mfma_f32_16x16x32_bf16(Ah.b, bl0, acc0, 0, 0, 0);
            acc0 = __builtin_amdgcn_mfma_f32_16x16x32_bf16(Al.b, bh0, acc0, 0, 0, 0);
            acc1 = __builtin_amdgcn_mfma_f32_16x16x32_bf16(Ah.b, bh1, acc1, 0, 0, 0);
            acc1 = __builtin_amdgcn_mfma_f32_16x16x32_bf16(Ah.b, bl1, acc1, 0, 0, 0);
            acc1 = __builtin_amdgcn_mfma_f32_16x16x32_bf16(Al.b, bh1, acc1, 0, 0, 0);
            acc2 = __builtin_amdgcn_mfma_f32_16x16x32_bf16(Ah.b, bh2, acc2, 0, 0, 0);
            acc2 = __builtin_amdgcn_mfma_f32_16x16x32_bf16(Ah.b, bl2, acc2, 0, 0, 0);
            acc2 = __builtin_amdgcn_mfma_f32_16x16x32_bf16(Al.b, bh2, acc2, 0, 0, 0);
            acc3 = __builtin_amdgcn_mfma_f32_16x16x32_bf16(Ah.b, bh3, acc3, 0, 0, 0);
            acc3 = __builtin_amdgcn_mfma_f32_16x16x32_bf16(Ah.b, bl3, acc3, 0, 0, 0);
            acc3 = __builtin_amdgcn_mfma_f32_16x16x32_bf16(Al.b, bh3, acc3, 0, 0, 0);
        }
    }
    #pragma unroll
    for (int n = 0; n < 4; ++n) {
        f32x4 a = (n == 0) ? acc0 : (n == 1) ? acc1 : (n == 2) ? acc2 : acc3;
        #pragma unroll
        for (int r = 0; r < 4; ++r) {
            int u = ub + w * 16 + (l4 << 2) + r;
            int tc = tb + (n << 4) + l15;
            atomicAdd(&numjoint[u * 256 + tc], a[r]);
        }
    }
}

// ---- Kernel Y: per-class GEMM (rows gathered via bidx) -> pyF fragments ----
// grid 256 = (y 0..127) x (t-half). K=n_y, hi/lo 3-term MFMA. y>=100: zeros.
__global__ __launch_bounds__(256, 2) void kY(const float* __restrict__ P01,
                                             const float* __restrict__ P23,
                                             const int* __restrict__ bidx,
                                             const int* __restrict__ off_g,
                                             const float* __restrict__ numjoint,
                                             short* __restrict__ pyF) {
    __shared__ short Bh[8 * 64 * 8];
    __shared__ short Bl[8 * 64 * 8];
    __shared__ short ct[4][16 * 128];
    __shared__ float aStage[32][258];
    __shared__ int sbidx[32];
    int y = blockIdx.x >> 1;
    int th = blockIdx.x & 1;
    int t = threadIdx.x;
    int lane = t & 63, w = t >> 6;
    int l15 = lane & 15, l4 = lane >> 4;
    int yt = y >> 4, yl = y & 15;

    if (y >= 100) {
        short8 z = {0, 0, 0, 0, 0, 0, 0, 0};
        #pragma unroll
        for (int ut = 0; ut < 4; ++ut)
            #pragma unroll
            for (int rep = 0; rep < 4; ++rep) {
                int c = (rep << 6) + lane;
                int ul = c >> 4, t8 = (c & 15) << 3;
                int u = (w << 6) + (ut << 4) + ul;
                int j0 = u * 256 + (th << 7) + t8;
                size_t sa = ((size_t)((j0 >> 5) * 8 + yt) * 64 + yl + (((j0 >> 3) & 3) << 4)) * 8;
                *(short8*)(pyF + sa) = z;
            }
        return;
    }

    int off = off_g[y];
    int n = off_g[y + 1] - off;
    int nk = (n + 31) >> 5;

    const f32x4 zero4 = {0.f, 0.f, 0.f, 0.f};
    f32x4 acc[4][8];
    #pragma unroll
    for (int a = 0; a < 4; ++a)
        #pragma unroll
        for (int b = 0; b < 8; ++b) acc[a][b] = zero4;

    int sr = t >> 3, sc = (t & 7) << 3;

    #pragma unroll 1
    for (int kc = 0; kc < nk; ++kc) {
        __syncthreads();
        if (t < 32) {
            int idx = off + kc * 32 + t;
            sbidx[t] = bidx[(idx < 1024) ? idx : 1023];   // clamp: A garbage x B zero
        }
        __syncthreads();
        // stage A rows (32 x 256, coalesced per row); out-of-range rows benign
        for (int it = 0; it < 32; ++it)
            aStage[it][t] = P01[sbidx[it] * 256 + t];
        // stage B (rows >= n zeroed)
        #pragma unroll
        for (int rep = 0; rep < 2; ++rep) {
            int tl0 = (rep << 6) + sc;
            int row = kc * 32 + sr;
            float vals[8];
            if (row < n) {
                const float* pb = P23 + (size_t)sbidx[sr] * 256 + (th << 7) + tl0;
                #pragma unroll
                for (int q = 0; q < 8; ++q) vals[q] = pb[q];
            } else {
                #pragma unroll
                for (int q = 0; q < 8; ++q) vals[q] = 0.f;
            }
            #pragma unroll
            for (int q = 0; q < 8; ++q) {
                short h, l;
                bsplit(vals[q], h, l);
                int tl = tl0 + q;
                int ad = (((tl >> 4) << 6) + (tl & 15) + ((sr >> 3) << 4)) * 8 + (sr & 7);
                Bh[ad] = h; Bl[ad] = l;
            }
        }
        __syncthreads();
        #pragma unroll
        for (int ut = 0; ut < 4; ++ut) {
            union { short8 s; bf16x8 b; } Ah, Al;
            #pragma unroll
            for (int q = 0; q < 8; ++q) {
                short h, l;
                bsplit(aStage[(l4 << 3) + q][(w << 6) + (ut << 4) + l15], h, l);
                Ah.s[q] = h; Al.s[q] = l;
            }
            #pragma unroll
            for (int tt = 0; tt < 8; ++tt) {
                bf16x8 bh = *(const bf16x8*)(Bh + ((tt << 6) + lane) * 8);
                bf16x8 bl = *(const bf16x8*)(Bl + ((tt << 6) + lane) * 8);
                acc[ut][tt] = __builtin_amdgcn_mfma_f32_16x16x32_bf16(Ah.b, bh, acc[ut][tt], 0, 0, 0);
                acc[ut][tt] = __builtin_amdgcn_mfma_f32_16x16x32_bf16(Ah.b, bl, acc[ut][tt], 0, 0, 0);
                acc[ut][tt] = __builtin_amdgcn_mfma_f32_16x16x32_bf16(Al.b, bh, acc[ut][tt], 0, 0, 0);
            }
        }
    }

    // epilogue: divide by numjoint, clip, per-wave LDS transpose, store pyF
    #pragma unroll
    for (int ut = 0; ut < 4; ++ut) {
        #pragma unroll
        for (int tt = 0; tt < 8; ++tt) {
            #pragma unroll
            for (int r = 0; r < 4; ++r) {
                int u = (w << 6) + (ut << 4) + (l4 << 2) + r;
                int tg = (th << 7) + (tt << 4) + l15;
                float nj = numjoint[u * 256 + tg];
                float q = fminf(fmaxf(acc[ut][tt][r], EPS) / fmaxf(nj, EPS), 1.0f);
                ct[w][((l4 << 2) + r) * 128 + (tt << 4) + l15] = bf16bits(q);
            }
        }
        asm volatile("s_waitcnt lgkmcnt(0)" ::: "memory");
        __builtin_amdgcn_sched_barrier(0);
        #pragma unroll
        for (int rep = 0; rep < 4; ++rep) {
            int c = (rep << 6) + lane;
            int ul = c >> 4, t8 = (c & 15) << 3;
            short8 v = *(const short8*)(ct[w] + ul * 128 + t8);
            int u = (w << 6) + (ut << 4) + ul;
            int j0 = u * 256 + (th << 7) + t8;
            size_t sa = ((size_t)((j0 >> 5) * 8 + yt) * 64 + yl + (((j0 >> 3) & 3) << 4)) * 8;
            *(short8*)(pyF + sa) = v;
        }
        asm volatile("s_waitcnt lgkmcnt(0)" ::: "memory");
        __builtin_amdgcn_sched_barrier(0);
    }
}

// ---- Kernel C: MFMA GEMM (unchanged).  part += P01*(py x P23^T) ------------
__global__ __launch_bounds__(512, 2) void kC(const short* __restrict__ P23s_hi,
                                             const float* __restrict__ P01T,
                                             const short* __restrict__ pyF,
                                             float* __restrict__ part) {
    __shared__ short Ahi[64 * 256];
    __shared__ float p01s[8 * 64];
    int t = threadIdx.x;
    int bb = blockIdx.x >> 5, uspl = blockIdx.x & 31;
    int bbase = bb << 6;
    int u0 = uspl << 3;

    #pragma unroll
    for (int r = 0; r < 4; ++r) {
        int c = r * 512 + t;
        *(short8*)(Ahi + c * 8) = *(const short8*)(P23s_hi + bbase * 256 + c * 8);
    }
    p01s[t] = P01T[(u0 + (t >> 6)) * 1024 + bbase + (t & 63)];
    __syncthreads();

    int lane = t & 63;
    int wave = t >> 6;
    int wb = wave >> 2, wy = wave & 3;
    int l15 = lane & 15, l4 = lane >> 4;
    int hi8 = l4 << 3;

    int rowA0 = wb * 32 + l15;
    int swz = (rowA0 & 7) << 3;
    const short* pA0h = Ahi + rowA0 * 256;
    const short* pA1h = pA0h + 16 * 256;

    const short* pf = pyF + (size_t)(uspl * 64 * 8 + wy * 2) * 512 + lane * 8;
    int y0 = wy * 32 + l15;

    const f32x4 zero4 = {0.f, 0.f, 0.f, 0.f};
    f32x4 P00 = zero4, P01v = zero4, P10 = zero4, P11 = zero4;
    bf16x8 W0, W1, X0, X1, Y0, Y1, Z0, Z1;

#define COMPUTE(CUR0, CUR1, KS)                                                  \
    {                                                                            \
        int aoff = ((KS) * 32 + hi8) ^ swz;                                      \
        bf16x8 a0h = *(const bf16x8*)(pA0h + aoff);                              \
        bf16x8 a1h = *(const bf16x8*)(pA1h + aoff);                              \
        f32x4 c00 = ((KS) == 0) ? zero4 : Q00;                                   \
        f32x4 c01 = ((KS) == 0) ? zero4 : Q01;                                   \
        f32x4 c10 = ((KS) == 0) ? zero4 : Q10;                                   \
        f32x4 c11 = ((KS) == 0) ? zero4 : Q11;                                   \
        c00 = __builtin_amdgcn_mfma_f32_16x16x32_bf16(a0h, CUR0, c00, 0, 0, 0);  \
        c10 = __builtin_amdgcn_mfma_f32_16x16x32_bf16(a1h, CUR0, c10, 0, 0, 0);  \
        c01 = __builtin_amdgcn_mfma_f32_16x16x32_bf16(a0h, CUR1, c01, 0, 0, 0);  \
        c11 = __builtin_amdgcn_mfma_f32_16x16x32_bf16(a1h, CUR1, c11, 0, 0, 0);  \
        Q00 = c00; Q01 = c01; Q10 = c10; Q11 = c11;                              \
    }
#define STEP(CUR0, CUR1, NXT0, NXT1, KS, S3)    \
    NXT0 = gload16(pf + (S3) * 4096);           \
    NXT1 = gload16(pf + (S3) * 4096 + 512);     \
    WAITV(6);                                   \
    COMPUTE(CUR0, CUR1, KS)

    {
        W0 = gload16(pf);        W1 = gload16(pf + 512);
        X0 = gload16(pf + 4096); X1 = gload16(pf + 4096 + 512);
        Y0 = gload16(pf + 8192); Y1 = gload16(pf + 8192 + 512);
    }

    #pragma unroll 1
    for (int uu = 0; uu < 7; ++uu) {
        int s0 = uu * 8;
        f32x4 Q00, Q01, Q10, Q11;
        STEP(W0, W1, Z0, Z1, 0, s0 + 3)
        STEP(X0, X1, W0, W1, 1, s0 + 4)
        STEP(Y0, Y1, X0, X1, 2, s0 + 5)
        STEP(Z0, Z1, Y0, Y1, 3, s0 + 6)
        STEP(W0, W1, Z0, Z1, 4, s0 + 7)
        STEP(X0, X1, W0, W1, 5, s0 + 8)
        STEP(Y0, Y1, X0, X1, 6, s0 + 9)
        STEP(Z0, Z1, Y0, Y1, 7, s0 + 10)
        f32x4 pv0 = *(const f32x4*)(p01s + uu * 64 + wb * 32 + (l4 << 2));
        f32x4 pv1 = *(const f32x4*)(p01s + uu * 64 + wb * 32 + 16 + (l4 << 2));
        P00 += pv0 * Q00; P01v += pv0 * Q01;
        P10 += pv1 * Q10; P11 += pv1 * Q11;
    }
    {
        f32x4 Q00, Q01, Q10, Q11;
        STEP(W0, W1, Z0, Z1, 0, 59)
        STEP(X0, X1, W0, W1, 1, 60)
        STEP(Y0, Y1, X0, X1, 2, 61)
        STEP(Z0, Z1, Y0, Y1, 3, 62)
        STEP(W0, W1, Z0, Z1, 4, 63)
        WAITV(4); COMPUTE(X0, X1, 5)
        WAITV(2); COMPUTE(Y0, Y1, 6)
        WAITV(0); COMPUTE(Z0, Z1, 7)
        f32x4 pv0 = *(const f32x4*)(p01s + 7 * 64 + wb * 32 + (l4 << 2));
        f32x4 pv1 = *(const f32x4*)(p01s + 7 * 64 + wb * 32 + 16 + (l4 << 2));
        P00 += pv0 * Q00; P01v += pv0 * Q01;
        P10 += pv1 * Q10; P11 += pv1 * Q11;
    }
#undef STEP
#undef COMPUTE

    size_t pbase = (size_t)uspl * 128 * 1024;
    {
        int bg0 = bbase + wb * 32 + (l4 << 2);
        int bg1 = bg0 + 16;
        *(f32x4*)(part + pbase + (size_t)y0 * 1024 + bg0) = P00;
        *(f32x4*)(part + pbase + (size_t)y0 * 1024 + bg1) = P10;
        *(f32x4*)(part + pbase + (size_t)(y0 + 16) * 1024 + bg0) = P01v;
        *(f32x4*)(part + pbase + (size_t)(y0 + 16) * 1024 + bg1) = P11;
    }
}

// ---- Kernel D: reduce 32 u-split partials -> out[b*100+y] ------------------
__global__ __launch_bounds__(256) void kD(const float* __restrict__ part,
                                          float* __restrict__ out) {
    int t = threadIdx.x;
    int y = blockIdx.x >> 2;
    int b = ((blockIdx.x & 3) << 8) + t;
    float s = 0.f;
    for (int q = 0; q < 32; ++q)
        s += part[(((size_t)q * 128 + y) << 10) + b];
    out[(size_t)b * 100 + y] = s;
}

extern "C" void kernel_launch(void* const* d_in, const int* in_sizes, int n_in,
                              void* d_out, int out_size, void* d_ws, size_t ws_size,
                              hipStream_t stream) {
    const float* logits = (const float*)d_in[0];
    const float* y_true = (const float*)d_in[1];
    float* out = (float*)d_out;

    char* ws = (char*)d_ws;
    float* P01      = (float*)(ws);                       // 1 MB
    float* P23      = (float*)(ws + (1u << 20));          // 1 MB
    float* P01T     = (float*)(ws + (2u << 20));          // 1 MB
    short* P23s_hi  = (short*)(ws + (3u << 20));          // 512 KB
    int*   lab      = (int*)(ws + (4u << 20));            // 4 KB
    int*   bidx     = (int*)(ws + (4u << 20) + 4096);
    int*   off_g    = (int*)(ws + (4u << 20) + 8192);     // 101 ints
    short* pyF      = (short*)(ws + (8u << 20));          // 16 MB fragment layout
    float* numjoint = (float*)(ws + (24u << 20));         // 256 KB
    float* part     = (float*)(ws + (40u << 20));         // 16 MB

    kA<<<1024, 256, 0, stream>>>(logits, y_true, P23, P01, P01T, P23s_hi, lab, numjoint);
    kSNJ<<<257, 256, 0, stream>>>(P01T, P23, lab, bidx, off_g, numjoint);
    kY<<<256, 256, 0, stream>>>(P01, P23, bidx, off_g, numjoint, pyF);
    kC<<<512, 512, 0, stream>>>(P23s_hi, P01T, pyF, part);
    kD<<<400, 256, 0, stream>>>(part, out);
}

// Round 17
// 70.546 us; speedup vs baseline: 1.6952x; 1.0765x over previous
//
#include <hip/hip_runtime.h>
#include <hip/hip_bf16.h>

#define EPS 1e-6f

typedef float f32x4 __attribute__((ext_vector_type(4)));
typedef __bf16 bf16x8 __attribute__((ext_vector_type(8)));
typedef short short8 __attribute__((ext_vector_type(8)));

static __device__ __forceinline__ short bf16bits(float x) {
    __hip_bfloat16 h = __float2bfloat16(x);
    short s;
    __builtin_memcpy(&s, &h, 2);
    return s;
}
static __device__ __forceinline__ void bsplit(float x, short& h, short& l) {
    __hip_bfloat16 hb = __float2bfloat16(x);
    __builtin_memcpy(&h, &hb, 2);
    float hf = __bfloat162float(hb);
    __hip_bfloat16 lb = __float2bfloat16(x - hf);
    __builtin_memcpy(&l, &lb, 2);
}

// Inline-asm loads for kC (forced counted-vmcnt pipeline, proven R11).
static __device__ __forceinline__ bf16x8 gload16(const short* p) {
    bf16x8 r;
    asm volatile("global_load_dwordx4 %0, %1, off"
                 : "=&v"(r) : "v"(p) : "memory");
    return r;
}
#define WAITV(N)                                                   \
    do {                                                           \
        asm volatile("s_waitcnt vmcnt(" #N ")" ::: "memory");      \
        __builtin_amdgcn_sched_barrier(0);                         \
    } while (0)

// ---- Kernel A: softmax + P23/P01/P01T + P23s_hi (swizzled) + zero numjoint -
__global__ __launch_bounds__(256) void kA(const float* __restrict__ logits,
                                          const float* __restrict__ y_true,
                                          float* __restrict__ P23,
                                          float* __restrict__ P01,
                                          float* __restrict__ P01T,
                                          short* __restrict__ P23s_hi,
                                          int* __restrict__ label,
                                          float* __restrict__ numjoint) {
    __shared__ float row[64];
    int b = blockIdx.x, t = threadIdx.x;
    if (t < 64) {
        float x = logits[b * 64 + t];
        float m = x;
        for (int mk = 8; mk >= 1; mk >>= 1) m = fmaxf(m, __shfl_xor(m, mk, 16));
        float e = __expf(x - m);
        float s = e;
        for (int mk = 8; mk >= 1; mk >>= 1) s += __shfl_xor(s, mk, 16);
        row[t] = e / s;
    }
    if (t >= 128 && t < 228) {
        int y = t - 128;
        if (y_true[b * 100 + y] > 0.5f) label[b] = y;
    }
    if (t < 64) numjoint[b * 64 + t] = 0.f;   // disjoint slices; done before kSNJ
    __syncthreads();
    int hi = t >> 4, lo = t & 15;
    float v01 = row[hi] * row[16 + lo];
    float v23 = row[32 + hi] * row[48 + lo];
    P01[b * 256 + t] = v01;
    P01T[t * 1024 + b] = v01;
    P23[b * 256 + t] = v23;
    int ts = t ^ ((b & 7) << 3);   // XOR swizzle (matches kC LDS read)
    P23s_hi[b * 256 + ts] = bf16bits(v23);
}

// ---- Kernel SNJ: blocks 0..255 = numjoint partial GEMMs (unsorted inputs,
// order-independent); block 256 = counting sort (bitmask ranks, 256 thr). ----
__global__ __launch_bounds__(256, 4) void kSNJ(const float* __restrict__ P01T,
                                               const float* __restrict__ P23,
                                               const int* __restrict__ label,
                                               int* __restrict__ bidx,
                                               int* __restrict__ off_g,
                                               float* __restrict__ numjoint) {
    int t = threadIdx.x;
    int bid = blockIdx.x;

    if (bid == 256) {   // ---- sort block ----
        __shared__ int lab[1024];
        __shared__ unsigned bm[101 * 32];
        __shared__ int hist[101];
        __shared__ int offs[101];
        for (int i = t; i < 1024; i += 256) lab[i] = label[i];
        if (t < 101) hist[t] = 0;
        for (int i = t; i < 101 * 32; i += 256) bm[i] = 0u;
        __syncthreads();
        for (int i = t; i < 1024; i += 256) {
            int my = lab[i];
            atomicAdd(&hist[my], 1);
            atomicOr(&bm[my * 32 + (i >> 5)], 1u << (i & 31));
        }
        __syncthreads();
        if (t == 0) {
            int s = 0;
            for (int y = 0; y < 101; ++y) { offs[y] = s; s += hist[y]; }
        }
        __syncthreads();
        for (int i = t; i < 1024; i += 256) {
            int my = lab[i];
            int w = i >> 5;
            int rank = 0;
            for (int q = 0; q < 32; ++q)
                if (q < w) rank += __popc(bm[my * 32 + q]);
            rank += __popc(bm[my * 32 + w] & ((1u << (i & 31)) - 1u));
            bidx[offs[my] + rank] = i;
        }
        if (t <= 100) off_g[t] = offs[t];
        return;
    }

    // ---- NJ slice: numjoint[u,t] += sum_{K-slice} P01[b,u]P23[b,t] ----
    __shared__ short Bh[4 * 64 * 8];
    __shared__ short Bl[4 * 64 * 8];
    int ub = (bid & 3) << 6;
    int tb = ((bid >> 2) & 3) << 6;
    int koff = (bid >> 4) << 6;          // 0..960, step 64
    int lane = t & 63, w = t >> 6;
    int l15 = lane & 15, l4 = lane >> 4;

    const float* pa = P01T + (size_t)(ub + w * 16 + l15) * 1024 + koff + (l4 << 3);
    int sr = t >> 3, sc = (t & 7) << 3;

    const f32x4 zero4 = {0.f, 0.f, 0.f, 0.f};
    f32x4 acc0 = zero4, acc1 = zero4, acc2 = zero4, acc3 = zero4;

    #pragma unroll
    for (int kc = 0; kc < 2; ++kc) {
        __syncthreads();
        {
            const float* pb = P23 + (size_t)(koff + kc * 32 + sr) * 256 + tb + sc;
            #pragma unroll
            for (int q = 0; q < 8; ++q) {
                short h, l;
                bsplit(pb[q], h, l);
                int tcl = sc + q;
                int ad = (((tcl >> 4) << 6) + (tcl & 15) + ((sr >> 3) << 4)) * 8 + (sr & 7);
                Bh[ad] = h; Bl[ad] = l;
            }
        }
        __syncthreads();
        union { short8 s; bf16x8 b; } Ah, Al;
        #pragma unroll
        for (int q = 0; q < 8; ++q) {
            short h, l;
            bsplit(pa[kc * 32 + q], h, l);
            Ah.s[q] = h; Al.s[q] = l;
        }
        {
            bf16x8 bh0 = *(const bf16x8*)(Bh + (lane) * 8);
            bf16x8 bl0 = *(const bf16x8*)(Bl + (lane) * 8);
            bf16x8 bh1 = *(const bf16x8*)(Bh + (64 + lane) * 8);
            bf16x8 bl1 = *(const bf16x8*)(Bl + (64 + lane) * 8);
            bf16x8 bh2 = *(const bf16x8*)(Bh + (128 + lane) * 8);
            bf16x8 bl2 = *(const bf16x8*)(Bl + (128 + lane) * 8);
            bf16x8 bh3 = *(const bf16x8*)(Bh + (192 + lane) * 8);
            bf16x8 bl3 = *(const bf16x8*)(Bl + (192 + lane) * 8);
            acc0 = __builtin_amdgcn_mfma_f32_16x16x32_bf16(Ah.b, bh0, acc0, 0, 0, 0);
            acc0 = __builtin_amdgcn_mfma_f32_16x16x32_bf16(Ah.b, bl0, acc0, 0, 0, 0);
            acc0 = __builtin_amdgcn_mfma_f32_16x16x32_bf16(Al.b, bh0, acc0, 0, 0, 0);
            acc1 = __builtin_amdgcn_mfma_f32_16x16x32_bf16(Ah.b, bh1, acc1, 0, 0, 0);
            acc1 = __builtin_amdgcn_mfma_f32_16x16x32_bf16(Ah.b, bl1, acc1, 0, 0, 0);
            acc1 = __builtin_amdgcn_mfma_f32_16x16x32_bf16(Al.b, bh1, acc1, 0, 0, 0);
            acc2 = __builtin_amdgcn_mfma_f32_16x16x32_bf16(Ah.b, bh2, acc2, 0, 0, 0);
            acc2 = __builtin_amdgcn_mfma_f32_16x16x32_bf16(Ah.b, bl2, acc2, 0, 0, 0);
            acc2 = __builtin_amdgcn_mfma_f32_16x16x32_bf16(Al.b, bh2, acc2, 0, 0, 0);
            acc3 = __builtin_amdgcn_mfma_f32_16x16x32_bf16(Ah.b, bh3, acc3, 0, 0, 0);
            acc3 = __builtin_amdgcn_mfma_f32_16x16x32_bf16(Ah.b, bl3, acc3, 0, 0, 0);
            acc3 = __builtin_amdgcn_mfma_f32_16x16x32_bf16(Al.b, bh3, acc3, 0, 0, 0);
        }
    }
    #pragma unroll
    for (int n = 0; n < 4; ++n) {
        f32x4 a = (n == 0) ? acc0 : (n == 1) ? acc1 : (n == 2) ? acc2 : acc3;
        #pragma unroll
        for (int r = 0; r < 4; ++r) {
            int u = ub + w * 16 + (l4 << 2) + r;
            int tc = tb + (n << 4) + l15;
            atomicAdd(&numjoint[u * 256 + tc], a[r]);
        }
    }
}

// ---- Kernel Y: per-class GEMM (rows gathered via bidx) -> pyF fragments ----
// grid 256 = (y 0..127) x (t-half). K=n_y, hi/lo 3-term MFMA. y>=100: zeros.
__global__ __launch_bounds__(256, 2) void kY(const float* __restrict__ P01,
                                             const float* __restrict__ P23,
                                             const int* __restrict__ bidx,
                                             const int* __restrict__ off_g,
                                             const float* __restrict__ numjoint,
                                             short* __restrict__ pyF) {
    __shared__ short Bh[8 * 64 * 8];
    __shared__ short Bl[8 * 64 * 8];
    __shared__ short ct[4][16 * 128];
    __shared__ float aStage[32][258];
    __shared__ int sbidx[32];
    int y = blockIdx.x >> 1;
    int th = blockIdx.x & 1;
    int t = threadIdx.x;
    int lane = t & 63, w = t >> 6;
    int l15 = lane & 15, l4 = lane >> 4;
    int yt = y >> 4, yl = y & 15;

    if (y >= 100) {
        short8 z = {0, 0, 0, 0, 0, 0, 0, 0};
        #pragma unroll
        for (int ut = 0; ut < 4; ++ut)
            #pragma unroll
            for (int rep = 0; rep < 4; ++rep) {
                int c = (rep << 6) + lane;
                int ul = c >> 4, t8 = (c & 15) << 3;
                int u = (w << 6) + (ut << 4) + ul;
                int j0 = u * 256 + (th << 7) + t8;
                size_t sa = ((size_t)((j0 >> 5) * 8 + yt) * 64 + yl + (((j0 >> 3) & 3) << 4)) * 8;
                *(short8*)(pyF + sa) = z;
            }
        return;
    }

    int off = off_g[y];
    int n = off_g[y + 1] - off;
    int nk = (n + 31) >> 5;

    const f32x4 zero4 = {0.f, 0.f, 0.f, 0.f};
    f32x4 acc[4][8];
    #pragma unroll
    for (int a = 0; a < 4; ++a)
        #pragma unroll
        for (int b = 0; b < 8; ++b) acc[a][b] = zero4;

    int sr = t >> 3, sc = (t & 7) << 3;

    #pragma unroll 1
    for (int kc = 0; kc < nk; ++kc) {
        __syncthreads();
        if (t < 32) {
            int idx = off + kc * 32 + t;
            sbidx[t] = bidx[(idx < 1024) ? idx : 1023];   // clamp: A garbage x B zero
        }
        __syncthreads();
        // stage A rows (32 x 256, coalesced per row); out-of-range rows benign
        for (int it = 0; it < 32; ++it)
            aStage[it][t] = P01[sbidx[it] * 256 + t];
        // stage B (rows >= n zeroed)
        #pragma unroll
        for (int rep = 0; rep < 2; ++rep) {
            int tl0 = (rep << 6) + sc;
            int row = kc * 32 + sr;
            float vals[8];
            if (row < n) {
                const float* pb = P23 + (size_t)sbidx[sr] * 256 + (th << 7) + tl0;
                #pragma unroll
                for (int q = 0; q < 8; ++q) vals[q] = pb[q];
            } else {
                #pragma unroll
                for (int q = 0; q < 8; ++q) vals[q] = 0.f;
            }
            #pragma unroll
            for (int q = 0; q < 8; ++q) {
                short h, l;
                bsplit(vals[q], h, l);
                int tl = tl0 + q;
                int ad = (((tl >> 4) << 6) + (tl & 15) + ((sr >> 3) << 4)) * 8 + (sr & 7);
                Bh[ad] = h; Bl[ad] = l;
            }
        }
        __syncthreads();
        #pragma unroll
        for (int ut = 0; ut < 4; ++ut) {
            union { short8 s; bf16x8 b; } Ah, Al;
            #pragma unroll
            for (int q = 0; q < 8; ++q) {
                short h, l;
                bsplit(aStage[(l4 << 3) + q][(w << 6) + (ut << 4) + l15], h, l);
                Ah.s[q] = h; Al.s[q] = l;
            }
            #pragma unroll
            for (int tt = 0; tt < 8; ++tt) {
                bf16x8 bh = *(const bf16x8*)(Bh + ((tt << 6) + lane) * 8);
                bf16x8 bl = *(const bf16x8*)(Bl + ((tt << 6) + lane) * 8);
                acc[ut][tt] = __builtin_amdgcn_mfma_f32_16x16x32_bf16(Ah.b, bh, acc[ut][tt], 0, 0, 0);
                acc[ut][tt] = __builtin_amdgcn_mfma_f32_16x16x32_bf16(Ah.b, bl, acc[ut][tt], 0, 0, 0);
                acc[ut][tt] = __builtin_amdgcn_mfma_f32_16x16x32_bf16(Al.b, bh, acc[ut][tt], 0, 0, 0);
            }
        }
    }

    // epilogue: divide by numjoint, clip, per-wave LDS transpose, store pyF
    #pragma unroll
    for (int ut = 0; ut < 4; ++ut) {
        #pragma unroll
        for (int tt = 0; tt < 8; ++tt) {
            #pragma unroll
            for (int r = 0; r < 4; ++r) {
                int u = (w << 6) + (ut << 4) + (l4 << 2) + r;
                int tg = (th << 7) + (tt << 4) + l15;
                float nj = numjoint[u * 256 + tg];
                float q = fminf(fmaxf(acc[ut][tt][r], EPS) / fmaxf(nj, EPS), 1.0f);
                ct[w][((l4 << 2) + r) * 128 + (tt << 4) + l15] = bf16bits(q);
            }
        }
        asm volatile("s_waitcnt lgkmcnt(0)" ::: "memory");
        __builtin_amdgcn_sched_barrier(0);
        #pragma unroll
        for (int rep = 0; rep < 4; ++rep) {
            int c = (rep << 6) + lane;
            int ul = c >> 4, t8 = (c & 15) << 3;
            short8 v = *(const short8*)(ct[w] + ul * 128 + t8);
            int u = (w << 6) + (ut << 4) + ul;
            int j0 = u * 256 + (th << 7) + t8;
            size_t sa = ((size_t)((j0 >> 5) * 8 + yt) * 64 + yl + (((j0 >> 3) & 3) << 4)) * 8;
            *(short8*)(pyF + sa) = v;
        }
        asm volatile("s_waitcnt lgkmcnt(0)" ::: "memory");
        __builtin_amdgcn_sched_barrier(0);
    }
}

// ---- Kernel C: MFMA GEMM, 4-wave (no wb B-read duplication; L2 traffic
// halved 512->256 MB).  part[uspl][y][b] += P01[b,u]*(py_u x P23^T).
// 256 thr = 4 waves (wy), wave tile 64b x 32y (m=4, n=2); block 64b x 128y x 8u.
// (256,2): 2 blocks/CU, VGPR cap 256 -> ~125-reg loop safe.
__global__ __launch_bounds__(256, 2) void kC(const short* __restrict__ P23s_hi,
                                             const float* __restrict__ P01T,
                                             const short* __restrict__ pyF,
                                             float* __restrict__ part) {
    __shared__ short Ahi[64 * 256];
    __shared__ float p01s[512];
    int t = threadIdx.x;
    int bb = blockIdx.x >> 5, uspl = blockIdx.x & 31;
    int bbase = bb << 6;
    int u0 = uspl << 3;

    #pragma unroll
    for (int r = 0; r < 8; ++r) {
        int c = r * 256 + t;
        *(short8*)(Ahi + c * 8) = *(const short8*)(P23s_hi + bbase * 256 + c * 8);
    }
    p01s[t] = P01T[(u0 + (t >> 6)) * 1024 + bbase + (t & 63)];
    p01s[256 + t] = P01T[(u0 + 4 + (t >> 6)) * 1024 + bbase + (t & 63)];
    __syncthreads();

    int lane = t & 63;
    int wy = t >> 6;                       // 4 waves = 4 y-slices
    int l15 = lane & 15, l4 = lane >> 4;
    int hi8 = l4 << 3;

    int swz = (l15 & 7) << 3;              // rows l15+{0,16,32,48}: same &7
    const short* pA0h = Ahi + l15 * 256;
    const short* pA1h = pA0h + 16 * 256;
    const short* pA2h = pA0h + 32 * 256;
    const short* pA3h = pA0h + 48 * 256;

    const short* pf = pyF + (size_t)(uspl * 512 + wy * 2) * 512 + lane * 8;
    int y0 = wy * 32 + l15;

    const f32x4 zero4 = {0.f, 0.f, 0.f, 0.f};
    f32x4 P00 = zero4, P01v = zero4, P10 = zero4, P11 = zero4;
    f32x4 P20 = zero4, P21 = zero4, P30 = zero4, P31 = zero4;
    bf16x8 W0, W1, X0, X1, Y0, Y1, Z0, Z1;

#define COMPUTE(CUR0, CUR1, KS)                                                  \
    {                                                                            \
        int aoff = ((KS) * 32 + hi8) ^ swz;                                      \
        bf16x8 a0h = *(const bf16x8*)(pA0h + aoff);                              \
        bf16x8 a1h = *(const bf16x8*)(pA1h + aoff);                              \
        bf16x8 a2h = *(const bf16x8*)(pA2h + aoff);                              \
        bf16x8 a3h = *(const bf16x8*)(pA3h + aoff);                              \
        f32x4 c00 = ((KS) == 0) ? zero4 : Q00;                                   \
        f32x4 c01 = ((KS) == 0) ? zero4 : Q01;                                   \
        f32x4 c10 = ((KS) == 0) ? zero4 : Q10;                                   \
        f32x4 c11 = ((KS) == 0) ? zero4 : Q11;                                   \
        f32x4 c20 = ((KS) == 0) ? zero4 : Q20;                                   \
        f32x4 c21 = ((KS) == 0) ? zero4 : Q21;                                   \
        f32x4 c30 = ((KS) == 0) ? zero4 : Q30;                                   \
        f32x4 c31 = ((KS) == 0) ? zero4 : Q31;                                   \
        c00 = __builtin_amdgcn_mfma_f32_16x16x32_bf16(a0h, CUR0, c00, 0, 0, 0);  \
        c10 = __builtin_amdgcn_mfma_f32_16x16x32_bf16(a1h, CUR0, c10, 0, 0, 0);  \
        c20 = __builtin_amdgcn_mfma_f32_16x16x32_bf16(a2h, CUR0, c20, 0, 0, 0);  \
        c30 = __builtin_amdgcn_mfma_f32_16x16x32_bf16(a3h, CUR0, c30, 0, 0, 0);  \
        c01 = __builtin_amdgcn_mfma_f32_16x16x32_bf16(a0h, CUR1, c01, 0, 0, 0);  \
        c11 = __builtin_amdgcn_mfma_f32_16x16x32_bf16(a1h, CUR1, c11, 0, 0, 0);  \
        c21 = __builtin_amdgcn_mfma_f32_16x16x32_bf16(a2h, CUR1, c21, 0, 0, 0);  \
        c31 = __builtin_amdgcn_mfma_f32_16x16x32_bf16(a3h, CUR1, c31, 0, 0, 0);  \
        Q00 = c00; Q01 = c01; Q10 = c10; Q11 = c11;                              \
        Q20 = c20; Q21 = c21; Q30 = c30; Q31 = c31;                              \
    }
#define STEP(CUR0, CUR1, NXT0, NXT1, KS, S3)    \
    NXT0 = gload16(pf + (S3) * 4096);           \
    NXT1 = gload16(pf + (S3) * 4096 + 512);     \
    WAITV(6);                                   \
    COMPUTE(CUR0, CUR1, KS)

    {
        W0 = gload16(pf);        W1 = gload16(pf + 512);
        X0 = gload16(pf + 4096); X1 = gload16(pf + 4096 + 512);
        Y0 = gload16(pf + 8192); Y1 = gload16(pf + 8192 + 512);
    }

    #pragma unroll 1
    for (int uu = 0; uu < 7; ++uu) {
        int s0 = uu * 8;
        f32x4 Q00, Q01, Q10, Q11, Q20, Q21, Q30, Q31;
        STEP(W0, W1, Z0, Z1, 0, s0 + 3)
        STEP(X0, X1, W0, W1, 1, s0 + 4)
        STEP(Y0, Y1, X0, X1, 2, s0 + 5)
        STEP(Z0, Z1, Y0, Y1, 3, s0 + 6)
        STEP(W0, W1, Z0, Z1, 4, s0 + 7)
        STEP(X0, X1, W0, W1, 5, s0 + 8)
        STEP(Y0, Y1, X0, X1, 6, s0 + 9)
        STEP(Z0, Z1, Y0, Y1, 7, s0 + 10)
        f32x4 pv0 = *(const f32x4*)(p01s + uu * 64 + (l4 << 2));
        f32x4 pv1 = *(const f32x4*)(p01s + uu * 64 + 16 + (l4 << 2));
        f32x4 pv2 = *(const f32x4*)(p01s + uu * 64 + 32 + (l4 << 2));
        f32x4 pv3 = *(const f32x4*)(p01s + uu * 64 + 48 + (l4 << 2));
        P00 += pv0 * Q00; P01v += pv0 * Q01;
        P10 += pv1 * Q10; P11 += pv1 * Q11;
        P20 += pv2 * Q20; P21 += pv2 * Q21;
        P30 += pv3 * Q30; P31 += pv3 * Q31;
    }
    {
        f32x4 Q00, Q01, Q10, Q11, Q20, Q21, Q30, Q31;
        STEP(W0, W1, Z0, Z1, 0, 59)
        STEP(X0, X1, W0, W1, 1, 60)
        STEP(Y0, Y1, X0, X1, 2, 61)
        STEP(Z0, Z1, Y0, Y1, 3, 62)
        STEP(W0, W1, Z0, Z1, 4, 63)
        WAITV(4); COMPUTE(X0, X1, 5)
        WAITV(2); COMPUTE(Y0, Y1, 6)
        WAITV(0); COMPUTE(Z0, Z1, 7)
        f32x4 pv0 = *(const f32x4*)(p01s + 7 * 64 + (l4 << 2));
        f32x4 pv1 = *(const f32x4*)(p01s + 7 * 64 + 16 + (l4 << 2));
        f32x4 pv2 = *(const f32x4*)(p01s + 7 * 64 + 32 + (l4 << 2));
        f32x4 pv3 = *(const f32x4*)(p01s + 7 * 64 + 48 + (l4 << 2));
        P00 += pv0 * Q00; P01v += pv0 * Q01;
        P10 += pv1 * Q10; P11 += pv1 * Q11;
        P20 += pv2 * Q20; P21 += pv2 * Q21;
        P30 += pv3 * Q30; P31 += pv3 * Q31;
    }
#undef STEP
#undef COMPUTE

    size_t pbase = (size_t)uspl * 128 * 1024;
    {
        int bg0 = bbase + (l4 << 2);
        size_t r0 = pbase + (size_t)y0 * 1024;
        size_t r1 = pbase + (size_t)(y0 + 16) * 1024;
        *(f32x4*)(part + r0 + bg0)      = P00;
        *(f32x4*)(part + r0 + bg0 + 16) = P10;
        *(f32x4*)(part + r0 + bg0 + 32) = P20;
        *(f32x4*)(part + r0 + bg0 + 48) = P30;
        *(f32x4*)(part + r1 + bg0)      = P01v;
        *(f32x4*)(part + r1 + bg0 + 16) = P11;
        *(f32x4*)(part + r1 + bg0 + 32) = P21;
        *(f32x4*)(part + r1 + bg0 + 48) = P31;
    }
}

// ---- Kernel D: reduce 32 u-split partials -> out[b*100+y] ------------------
__global__ __launch_bounds__(256) void kD(const float* __restrict__ part,
                                          float* __restrict__ out) {
    int t = threadIdx.x;
    int y = blockIdx.x >> 2;
    int b = ((blockIdx.x & 3) << 8) + t;
    float s = 0.f;
    for (int q = 0; q < 32; ++q)
        s += part[(((size_t)q * 128 + y) << 10) + b];
    out[(size_t)b * 100 + y] = s;
}

extern "C" void kernel_launch(void* const* d_in, const int* in_sizes, int n_in,
                              void* d_out, int out_size, void* d_ws, size_t ws_size,
                              hipStream_t stream) {
    const float* logits = (const float*)d_in[0];
    const float* y_true = (const float*)d_in[1];
    float* out = (float*)d_out;

    char* ws = (char*)d_ws;
    float* P01      = (float*)(ws);                       // 1 MB
    float* P23      = (float*)(ws + (1u << 20));          // 1 MB
    float* P01T     = (float*)(ws + (2u << 20));          // 1 MB
    short* P23s_hi  = (short*)(ws + (3u << 20));          // 512 KB
    int*   lab      = (int*)(ws + (4u << 20));            // 4 KB
    int*   bidx     = (int*)(ws + (4u << 20) + 4096);
    int*   off_g    = (int*)(ws + (4u << 20) + 8192);     // 101 ints
    short* pyF      = (short*)(ws + (8u << 20));          // 16 MB fragment layout
    float* numjoint = (float*)(ws + (24u << 20));         // 256 KB
    float* part     = (float*)(ws + (40u << 20));         // 16 MB

    kA<<<1024, 256, 0, stream>>>(logits, y_true, P23, P01, P01T, P23s_hi, lab, numjoint);
    kSNJ<<<257, 256, 0, stream>>>(P01T, P23, lab, bidx, off_g, numjoint);
    kY<<<256, 256, 0, stream>>>(P01, P23, bidx, off_g, numjoint, pyF);
    kC<<<512, 256, 0, stream>>>(P23s_hi, P01T, pyF, part);
    kD<<<400, 256, 0, stream>>>(part, out);
}

// Round 18
// 67.033 us; speedup vs baseline: 1.7840x; 1.0524x over previous
//
#include <hip/hip_runtime.h>
#include <hip/hip_bf16.h>

#define EPS 1e-6f

typedef float f32x4 __attribute__((ext_vector_type(4)));
typedef __bf16 bf16x8 __attribute__((ext_vector_type(8)));
typedef short short8 __attribute__((ext_vector_type(8)));

static __device__ __forceinline__ short bf16bits(float x) {
    __hip_bfloat16 h = __float2bfloat16(x);
    short s;
    __builtin_memcpy(&s, &h, 2);
    return s;
}
static __device__ __forceinline__ void bsplit(float x, short& h, short& l) {
    __hip_bfloat16 hb = __float2bfloat16(x);
    __builtin_memcpy(&h, &hb, 2);
    float hf = __bfloat162float(hb);
    __hip_bfloat16 lb = __float2bfloat16(x - hf);
    __builtin_memcpy(&l, &lb, 2);
}

// Inline-asm loads for kC (forced counted-vmcnt pipeline, proven R11).
static __device__ __forceinline__ bf16x8 gload16(const short* p) {
    bf16x8 r;
    asm volatile("global_load_dwordx4 %0, %1, off"
                 : "=&v"(r) : "v"(p) : "memory");
    return r;
}
#define WAITV(N)                                                   \
    do {                                                           \
        asm volatile("s_waitcnt vmcnt(" #N ")" ::: "memory");      \
        __builtin_amdgcn_sched_barrier(0);                         \
    } while (0)

// ---- Kernel A: softmax + P23/P01/P01T + P23s_hi (swizzled) + zero numjoint -
__global__ __launch_bounds__(256) void kA(const float* __restrict__ logits,
                                          const float* __restrict__ y_true,
                                          float* __restrict__ P23,
                                          float* __restrict__ P01,
                                          float* __restrict__ P01T,
                                          short* __restrict__ P23s_hi,
                                          int* __restrict__ label,
                                          float* __restrict__ numjoint) {
    __shared__ float row[64];
    int b = blockIdx.x, t = threadIdx.x;
    if (t < 64) {
        float x = logits[b * 64 + t];
        float m = x;
        for (int mk = 8; mk >= 1; mk >>= 1) m = fmaxf(m, __shfl_xor(m, mk, 16));
        float e = __expf(x - m);
        float s = e;
        for (int mk = 8; mk >= 1; mk >>= 1) s += __shfl_xor(s, mk, 16);
        row[t] = e / s;
    }
    if (t >= 128 && t < 228) {
        int y = t - 128;
        if (y_true[b * 100 + y] > 0.5f) label[b] = y;
    }
    if (t < 64) numjoint[b * 64 + t] = 0.f;   // disjoint slices; done before kSNJ
    __syncthreads();
    int hi = t >> 4, lo = t & 15;
    float v01 = row[hi] * row[16 + lo];
    float v23 = row[32 + hi] * row[48 + lo];
    P01[b * 256 + t] = v01;
    P01T[t * 1024 + b] = v01;
    P23[b * 256 + t] = v23;
    int ts = t ^ ((b & 7) << 3);   // XOR swizzle (matches kC LDS read)
    P23s_hi[b * 256 + ts] = bf16bits(v23);
}

// ---- Kernel SNJ: blocks 0..511 = numjoint partial GEMMs (K=32 slices,
// unsorted inputs, order-independent); block 512 = counting sort. ------------
__global__ __launch_bounds__(256, 4) void kSNJ(const float* __restrict__ P01T,
                                               const float* __restrict__ P23,
                                               const int* __restrict__ label,
                                               int* __restrict__ bidx,
                                               int* __restrict__ off_g,
                                               float* __restrict__ numjoint) {
    int t = threadIdx.x;
    int bid = blockIdx.x;

    if (bid == 512) {   // ---- sort block ----
        __shared__ int lab[1024];
        __shared__ unsigned bm[101 * 32];
        __shared__ int hist[101];
        __shared__ int offs[101];
        for (int i = t; i < 1024; i += 256) lab[i] = label[i];
        if (t < 101) hist[t] = 0;
        for (int i = t; i < 101 * 32; i += 256) bm[i] = 0u;
        __syncthreads();
        for (int i = t; i < 1024; i += 256) {
            int my = lab[i];
            atomicAdd(&hist[my], 1);
            atomicOr(&bm[my * 32 + (i >> 5)], 1u << (i & 31));
        }
        __syncthreads();
        if (t == 0) {
            int s = 0;
            for (int y = 0; y < 101; ++y) { offs[y] = s; s += hist[y]; }
        }
        __syncthreads();
        for (int i = t; i < 1024; i += 256) {
            int my = lab[i];
            int w = i >> 5;
            int rank = 0;
            for (int q = 0; q < 32; ++q)
                if (q < w) rank += __popc(bm[my * 32 + q]);
            rank += __popc(bm[my * 32 + w] & ((1u << (i & 31)) - 1u));
            bidx[offs[my] + rank] = i;
        }
        if (t <= 100) off_g[t] = offs[t];
        return;
    }

    // ---- NJ slice: numjoint[u,t] += sum_{32-row K-slice} P01[b,u]P23[b,t] --
    __shared__ short Bh[4 * 64 * 8];
    __shared__ short Bl[4 * 64 * 8];
    int ub = (bid & 3) << 6;
    int tb = ((bid >> 2) & 3) << 6;
    int koff = (bid >> 4) << 5;          // 0..992, step 32
    int lane = t & 63, w = t >> 6;
    int l15 = lane & 15, l4 = lane >> 4;

    const float* pa = P01T + (size_t)(ub + w * 16 + l15) * 1024 + koff + (l4 << 3);
    int sr = t >> 3, sc = (t & 7) << 3;

    const f32x4 zero4 = {0.f, 0.f, 0.f, 0.f};
    f32x4 acc0 = zero4, acc1 = zero4, acc2 = zero4, acc3 = zero4;

    {
        const float* pb = P23 + (size_t)(koff + sr) * 256 + tb + sc;
        #pragma unroll
        for (int q = 0; q < 8; ++q) {
            short h, l;
            bsplit(pb[q], h, l);
            int tcl = sc + q;
            int ad = (((tcl >> 4) << 6) + (tcl & 15) + ((sr >> 3) << 4)) * 8 + (sr & 7);
            Bh[ad] = h; Bl[ad] = l;
        }
    }
    __syncthreads();
    union { short8 s; bf16x8 b; } Ah, Al;
    #pragma unroll
    for (int q = 0; q < 8; ++q) {
        short h, l;
        bsplit(pa[q], h, l);
        Ah.s[q] = h; Al.s[q] = l;
    }
    {
        bf16x8 bh0 = *(const bf16x8*)(Bh + (lane) * 8);
        bf16x8 bl0 = *(const bf16x8*)(Bl + (lane) * 8);
        bf16x8 bh1 = *(const bf16x8*)(Bh + (64 + lane) * 8);
        bf16x8 bl1 = *(const bf16x8*)(Bl + (64 + lane) * 8);
        bf16x8 bh2 = *(const bf16x8*)(Bh + (128 + lane) * 8);
        bf16x8 bl2 = *(const bf16x8*)(Bl + (128 + lane) * 8);
        bf16x8 bh3 = *(const bf16x8*)(Bh + (192 + lane) * 8);
        bf16x8 bl3 = *(const bf16x8*)(Bl + (192 + lane) * 8);
        acc0 = __builtin_amdgcn_mfma_f32_16x16x32_bf16(Ah.b, bh0, acc0, 0, 0, 0);
        acc0 = __builtin_amdgcn_mfma_f32_16x16x32_bf16(Ah.b, bl0, acc0, 0, 0, 0);
        acc0 = __builtin_amdgcn_mfma_f32_16x16x32_bf16(Al.b, bh0, acc0, 0, 0, 0);
        acc1 = __builtin_amdgcn_mfma_f32_16x16x32_bf16(Ah.b, bh1, acc1, 0, 0, 0);
        acc1 = __builtin_amdgcn_mfma_f32_16x16x32_bf16(Ah.b, bl1, acc1, 0, 0, 0);
        acc1 = __builtin_amdgcn_mfma_f32_16x16x32_bf16(Al.b, bh1, acc1, 0, 0, 0);
        acc2 = __builtin_amdgcn_mfma_f32_16x16x32_bf16(Ah.b, bh2, acc2, 0, 0, 0);
        acc2 = __builtin_amdgcn_mfma_f32_16x16x32_bf16(Ah.b, bl2, acc2, 0, 0, 0);
        acc2 = __builtin_amdgcn_mfma_f32_16x16x32_bf16(Al.b, bh2, acc2, 0, 0, 0);
        acc3 = __builtin_amdgcn_mfma_f32_16x16x32_bf16(Ah.b, bh3, acc3, 0, 0, 0);
        acc3 = __builtin_amdgcn_mfma_f32_16x16x32_bf16(Ah.b, bl3, acc3, 0, 0, 0);
        acc3 = __builtin_amdgcn_mfma_f32_16x16x32_bf16(Al.b, bh3, acc3, 0, 0, 0);
    }
    #pragma unroll
    for (int n = 0; n < 4; ++n) {
        f32x4 a = (n == 0) ? acc0 : (n == 1) ? acc1 : (n == 2) ? acc2 : acc3;
        #pragma unroll
        for (int r = 0; r < 4; ++r) {
            int u = ub + w * 16 + (l4 << 2) + r;
            int tc = tb + (n << 4) + l15;
            atomicAdd(&numjoint[u * 256 + tc], a[r]);
        }
    }
}

// ---- Kernel Y: per-class GEMM (rows gathered via bidx) -> pyF fragments ----
// grid 512 = (y 0..127) x (t-quarter). Block 256u x 64t, K=n_y. y>=100: zeros.
__global__ __launch_bounds__(256, 2) void kY(const float* __restrict__ P01,
                                             const float* __restrict__ P23,
                                             const int* __restrict__ bidx,
                                             const int* __restrict__ off_g,
                                             const float* __restrict__ numjoint,
                                             short* __restrict__ pyF) {
    __shared__ short Bh[4 * 64 * 8];
    __shared__ short Bl[4 * 64 * 8];
    __shared__ short ct[4][16 * 64];
    __shared__ float aStage[32][258];
    __shared__ int sbidx[32];
    int y = blockIdx.x >> 2;
    int qd = blockIdx.x & 3;            // t-quarter (64 cols)
    int t = threadIdx.x;
    int lane = t & 63, w = t >> 6;
    int l15 = lane & 15, l4 = lane >> 4;
    int yt = y >> 4, yl = y & 15;

    if (y >= 100) {
        short8 z = {0, 0, 0, 0, 0, 0, 0, 0};
        #pragma unroll
        for (int ut = 0; ut < 4; ++ut)
            #pragma unroll
            for (int rep = 0; rep < 2; ++rep) {
                int c = (rep << 6) + lane;
                int ul = c >> 3, t8 = (c & 7) << 3;
                int u = (w << 6) + (ut << 4) + ul;
                int j0 = u * 256 + (qd << 6) + t8;
                size_t sa = ((size_t)((j0 >> 5) * 8 + yt) * 64 + yl + (((j0 >> 3) & 3) << 4)) * 8;
                *(short8*)(pyF + sa) = z;
            }
        return;
    }

    int off = off_g[y];
    int n = off_g[y + 1] - off;
    int nk = (n + 31) >> 5;

    const f32x4 zero4 = {0.f, 0.f, 0.f, 0.f};
    f32x4 acc[4][4];
    #pragma unroll
    for (int a = 0; a < 4; ++a)
        #pragma unroll
        for (int b = 0; b < 4; ++b) acc[a][b] = zero4;

    int sr = t >> 3, sc = (t & 7) << 3;

    #pragma unroll 1
    for (int kc = 0; kc < nk; ++kc) {
        __syncthreads();
        if (t < 32) {
            int idx = off + kc * 32 + t;
            sbidx[t] = bidx[(idx < 1024) ? idx : 1023];   // clamp: A garbage x B zero
        }
        __syncthreads();
        // stage A rows (32 x 256, coalesced per row); out-of-range rows benign
        for (int it = 0; it < 32; ++it)
            aStage[it][t] = P01[sbidx[it] * 256 + t];
        // stage B (32 x 64; rows >= n zeroed)
        {
            int row = kc * 32 + sr;
            float vals[8];
            if (row < n) {
                const float* pb = P23 + (size_t)sbidx[sr] * 256 + (qd << 6) + sc;
                #pragma unroll
                for (int q = 0; q < 8; ++q) vals[q] = pb[q];
            } else {
                #pragma unroll
                for (int q = 0; q < 8; ++q) vals[q] = 0.f;
            }
            #pragma unroll
            for (int q = 0; q < 8; ++q) {
                short h, l;
                bsplit(vals[q], h, l);
                int tl = sc + q;
                int ad = (((tl >> 4) << 6) + (tl & 15) + ((sr >> 3) << 4)) * 8 + (sr & 7);
                Bh[ad] = h; Bl[ad] = l;
            }
        }
        __syncthreads();
        #pragma unroll
        for (int ut = 0; ut < 4; ++ut) {
            union { short8 s; bf16x8 b; } Ah, Al;
            #pragma unroll
            for (int q = 0; q < 8; ++q) {
                short h, l;
                bsplit(aStage[(l4 << 3) + q][(w << 6) + (ut << 4) + l15], h, l);
                Ah.s[q] = h; Al.s[q] = l;
            }
            #pragma unroll
            for (int tt = 0; tt < 4; ++tt) {
                bf16x8 bh = *(const bf16x8*)(Bh + ((tt << 6) + lane) * 8);
                bf16x8 bl = *(const bf16x8*)(Bl + ((tt << 6) + lane) * 8);
                acc[ut][tt] = __builtin_amdgcn_mfma_f32_16x16x32_bf16(Ah.b, bh, acc[ut][tt], 0, 0, 0);
                acc[ut][tt] = __builtin_amdgcn_mfma_f32_16x16x32_bf16(Ah.b, bl, acc[ut][tt], 0, 0, 0);
                acc[ut][tt] = __builtin_amdgcn_mfma_f32_16x16x32_bf16(Al.b, bh, acc[ut][tt], 0, 0, 0);
            }
        }
    }

    // epilogue: divide by numjoint, clip, per-wave LDS transpose, store pyF
    #pragma unroll
    for (int ut = 0; ut < 4; ++ut) {
        #pragma unroll
        for (int tt = 0; tt < 4; ++tt) {
            #pragma unroll
            for (int r = 0; r < 4; ++r) {
                int u = (w << 6) + (ut << 4) + (l4 << 2) + r;
                int tg = (qd << 6) + (tt << 4) + l15;
                float nj = numjoint[u * 256 + tg];
                float q = fminf(fmaxf(acc[ut][tt][r], EPS) / fmaxf(nj, EPS), 1.0f);
                ct[w][((l4 << 2) + r) * 64 + (tt << 4) + l15] = bf16bits(q);
            }
        }
        asm volatile("s_waitcnt lgkmcnt(0)" ::: "memory");
        __builtin_amdgcn_sched_barrier(0);
        #pragma unroll
        for (int rep = 0; rep < 2; ++rep) {
            int c = (rep << 6) + lane;
            int ul = c >> 3, t8 = (c & 7) << 3;
            short8 v = *(const short8*)(ct[w] + ul * 64 + t8);
            int u = (w << 6) + (ut << 4) + ul;
            int j0 = u * 256 + (qd << 6) + t8;
            size_t sa = ((size_t)((j0 >> 5) * 8 + yt) * 64 + yl + (((j0 >> 3) & 3) << 4)) * 8;
            *(short8*)(pyF + sa) = v;
        }
        asm volatile("s_waitcnt lgkmcnt(0)" ::: "memory");
        __builtin_amdgcn_sched_barrier(0);
    }
}

// ---- Kernel C: MFMA GEMM, 4-wave, 3 blocks/CU. part += P01*(py x P23^T) ----
// 256 thr = 4 waves (wy), wave tile 64b x 32y; block 64b x 128y x 8u.
// (256,3): 3 blocks/CU, VGPR cap ~170 (loop ~135) -> more latency hiding.
__global__ __launch_bounds__(256, 3) void kC(const short* __restrict__ P23s_hi,
                                             const float* __restrict__ P01T,
                                             const short* __restrict__ pyF,
                                             float* __restrict__ part) {
    __shared__ short Ahi[64 * 256];
    __shared__ float p01s[512];
    int t = threadIdx.x;
    int bb = blockIdx.x >> 5, uspl = blockIdx.x & 31;
    int bbase = bb << 6;
    int u0 = uspl << 3;

    #pragma unroll
    for (int r = 0; r < 8; ++r) {
        int c = r * 256 + t;
        *(short8*)(Ahi + c * 8) = *(const short8*)(P23s_hi + bbase * 256 + c * 8);
    }
    p01s[t] = P01T[(u0 + (t >> 6)) * 1024 + bbase + (t & 63)];
    p01s[256 + t] = P01T[(u0 + 4 + (t >> 6)) * 1024 + bbase + (t & 63)];
    __syncthreads();

    int lane = t & 63;
    int wy = t >> 6;                       // 4 waves = 4 y-slices
    int l15 = lane & 15, l4 = lane >> 4;
    int hi8 = l4 << 3;

    int swz = (l15 & 7) << 3;              // rows l15+{0,16,32,48}: same &7
    const short* pA0h = Ahi + l15 * 256;
    const short* pA1h = pA0h + 16 * 256;
    const short* pA2h = pA0h + 32 * 256;
    const short* pA3h = pA0h + 48 * 256;

    const short* pf = pyF + (size_t)(uspl * 512 + wy * 2) * 512 + lane * 8;
    int y0 = wy * 32 + l15;

    const f32x4 zero4 = {0.f, 0.f, 0.f, 0.f};
    f32x4 P00 = zero4, P01v = zero4, P10 = zero4, P11 = zero4;
    f32x4 P20 = zero4, P21 = zero4, P30 = zero4, P31 = zero4;
    bf16x8 W0, W1, X0, X1, Y0, Y1, Z0, Z1;

#define COMPUTE(CUR0, CUR1, KS)                                                  \
    {                                                                            \
        int aoff = ((KS) * 32 + hi8) ^ swz;                                      \
        bf16x8 a0h = *(const bf16x8*)(pA0h + aoff);                              \
        bf16x8 a1h = *(const bf16x8*)(pA1h + aoff);                              \
        bf16x8 a2h = *(const bf16x8*)(pA2h + aoff);                              \
        bf16x8 a3h = *(const bf16x8*)(pA3h + aoff);                              \
        f32x4 c00 = ((KS) == 0) ? zero4 : Q00;                                   \
        f32x4 c01 = ((KS) == 0) ? zero4 : Q01;                                   \
        f32x4 c10 = ((KS) == 0) ? zero4 : Q10;                                   \
        f32x4 c11 = ((KS) == 0) ? zero4 : Q11;                                   \
        f32x4 c20 = ((KS) == 0) ? zero4 : Q20;                                   \
        f32x4 c21 = ((KS) == 0) ? zero4 : Q21;                                   \
        f32x4 c30 = ((KS) == 0) ? zero4 : Q30;                                   \
        f32x4 c31 = ((KS) == 0) ? zero4 : Q31;                                   \
        c00 = __builtin_amdgcn_mfma_f32_16x16x32_bf16(a0h, CUR0, c00, 0, 0, 0);  \
        c10 = __builtin_amdgcn_mfma_f32_16x16x32_bf16(a1h, CUR0, c10, 0, 0, 0);  \
        c20 = __builtin_amdgcn_mfma_f32_16x16x32_bf16(a2h, CUR0, c20, 0, 0, 0);  \
        c30 = __builtin_amdgcn_mfma_f32_16x16x32_bf16(a3h, CUR0, c30, 0, 0, 0);  \
        c01 = __builtin_amdgcn_mfma_f32_16x16x32_bf16(a0h, CUR1, c01, 0, 0, 0);  \
        c11 = __builtin_amdgcn_mfma_f32_16x16x32_bf16(a1h, CUR1, c11, 0, 0, 0);  \
        c21 = __builtin_amdgcn_mfma_f32_16x16x32_bf16(a2h, CUR1, c21, 0, 0, 0);  \
        c31 = __builtin_amdgcn_mfma_f32_16x16x32_bf16(a3h, CUR1, c31, 0, 0, 0);  \
        Q00 = c00; Q01 = c01; Q10 = c10; Q11 = c11;                              \
        Q20 = c20; Q21 = c21; Q30 = c30; Q31 = c31;                              \
    }
#define STEP(CUR0, CUR1, NXT0, NXT1, KS, S3)    \
    NXT0 = gload16(pf + (S3) * 4096);           \
    NXT1 = gload16(pf + (S3) * 4096 + 512);     \
    WAITV(6);                                   \
    COMPUTE(CUR0, CUR1, KS)

    {
        W0 = gload16(pf);        W1 = gload16(pf + 512);
        X0 = gload16(pf + 4096); X1 = gload16(pf + 4096 + 512);
        Y0 = gload16(pf + 8192); Y1 = gload16(pf + 8192 + 512);
    }

    #pragma unroll 1
    for (int uu = 0; uu < 7; ++uu) {
        int s0 = uu * 8;
        f32x4 Q00, Q01, Q10, Q11, Q20, Q21, Q30, Q31;
        STEP(W0, W1, Z0, Z1, 0, s0 + 3)
        STEP(X0, X1, W0, W1, 1, s0 + 4)
        STEP(Y0, Y1, X0, X1, 2, s0 + 5)
        STEP(Z0, Z1, Y0, Y1, 3, s0 + 6)
        STEP(W0, W1, Z0, Z1, 4, s0 + 7)
        STEP(X0, X1, W0, W1, 5, s0 + 8)
        STEP(Y0, Y1, X0, X1, 6, s0 + 9)
        STEP(Z0, Z1, Y0, Y1, 7, s0 + 10)
        f32x4 pv0 = *(const f32x4*)(p01s + uu * 64 + (l4 << 2));
        f32x4 pv1 = *(const f32x4*)(p01s + uu * 64 + 16 + (l4 << 2));
        f32x4 pv2 = *(const f32x4*)(p01s + uu * 64 + 32 + (l4 << 2));
        f32x4 pv3 = *(const f32x4*)(p01s + uu * 64 + 48 + (l4 << 2));
        P00 += pv0 * Q00; P01v += pv0 * Q01;
        P10 += pv1 * Q10; P11 += pv1 * Q11;
        P20 += pv2 * Q20; P21 += pv2 * Q21;
        P30 += pv3 * Q30; P31 += pv3 * Q31;
    }
    {
        f32x4 Q00, Q01, Q10, Q11, Q20, Q21, Q30, Q31;
        STEP(W0, W1, Z0, Z1, 0, 59)
        STEP(X0, X1, W0, W1, 1, 60)
        STEP(Y0, Y1, X0, X1, 2, 61)
        STEP(Z0, Z1, Y0, Y1, 3, 62)
        STEP(W0, W1, Z0, Z1, 4, 63)
        WAITV(4); COMPUTE(X0, X1, 5)
        WAITV(2); COMPUTE(Y0, Y1, 6)
        WAITV(0); COMPUTE(Z0, Z1, 7)
        f32x4 pv0 = *(const f32x4*)(p01s + 7 * 64 + (l4 << 2));
        f32x4 pv1 = *(const f32x4*)(p01s + 7 * 64 + 16 + (l4 << 2));
        f32x4 pv2 = *(const f32x4*)(p01s + 7 * 64 + 32 + (l4 << 2));
        f32x4 pv3 = *(const f32x4*)(p01s + 7 * 64 + 48 + (l4 << 2));
        P00 += pv0 * Q00; P01v += pv0 * Q01;
        P10 += pv1 * Q10; P11 += pv1 * Q11;
        P20 += pv2 * Q20; P21 += pv2 * Q21;
        P30 += pv3 * Q30; P31 += pv3 * Q31;
    }
#undef STEP
#undef COMPUTE

    size_t pbase = (size_t)uspl * 128 * 1024;
    {
        int bg0 = bbase + (l4 << 2);
        size_t r0 = pbase + (size_t)y0 * 1024;
        size_t r1 = pbase + (size_t)(y0 + 16) * 1024;
        *(f32x4*)(part + r0 + bg0)      = P00;
        *(f32x4*)(part + r0 + bg0 + 16) = P10;
        *(f32x4*)(part + r0 + bg0 + 32) = P20;
        *(f32x4*)(part + r0 + bg0 + 48) = P30;
        *(f32x4*)(part + r1 + bg0)      = P01v;
        *(f32x4*)(part + r1 + bg0 + 16) = P11;
        *(f32x4*)(part + r1 + bg0 + 32) = P21;
        *(f32x4*)(part + r1 + bg0 + 48) = P31;
    }
}

// ---- Kernel D: reduce 32 u-split partials -> out[b*100+y] ------------------
__global__ __launch_bounds__(256) void kD(const float* __restrict__ part,
                                          float* __restrict__ out) {
    int t = threadIdx.x;
    int y = blockIdx.x >> 2;
    int b = ((blockIdx.x & 3) << 8) + t;
    float s = 0.f;
    for (int q = 0; q < 32; ++q)
        s += part[(((size_t)q * 128 + y) << 10) + b];
    out[(size_t)b * 100 + y] = s;
}

extern "C" void kernel_launch(void* const* d_in, const int* in_sizes, int n_in,
                              void* d_out, int out_size, void* d_ws, size_t ws_size,
                              hipStream_t stream) {
    const float* logits = (const float*)d_in[0];
    const float* y_true = (const float*)d_in[1];
    float* out = (float*)d_out;

    char* ws = (char*)d_ws;
    float* P01      = (float*)(ws);                       // 1 MB
    float* P23      = (float*)(ws + (1u << 20));          // 1 MB
    float* P01T     = (float*)(ws + (2u << 20));          // 1 MB
    short* P23s_hi  = (short*)(ws + (3u << 20));          // 512 KB
    int*   lab      = (int*)(ws + (4u << 20));            // 4 KB
    int*   bidx     = (int*)(ws + (4u << 20) + 4096);
    int*   off_g    = (int*)(ws + (4u << 20) + 8192);     // 101 ints
    short* pyF      = (short*)(ws + (8u << 20));          // 16 MB fragment layout
    float* numjoint = (float*)(ws + (24u << 20));         // 256 KB
    float* part     = (float*)(ws + (40u << 20));         // 16 MB

    kA<<<1024, 256, 0, stream>>>(logits, y_true, P23, P01, P01T, P23s_hi, lab, numjoint);
    kSNJ<<<513, 256, 0, stream>>>(P01T, P23, lab, bidx, off_g, numjoint);
    kY<<<512, 256, 0, stream>>>(P01, P23, bidx, off_g, numjoint, pyF);
    kC<<<512, 256, 0, stream>>>(P23s_hi, P01T, pyF, part);
    kD<<<400, 256, 0, stream>>>(part, out);
}